// Round 17
// baseline (2474.850 us; speedup 1.0000x reference)
//
#include <hip/hip_runtime.h>

#define EPS_BN 1e-5f

typedef __bf16 bf16x8 __attribute__((ext_vector_type(8)));
typedef float f32x4 __attribute__((ext_vector_type(4)));
typedef unsigned short us8 __attribute__((ext_vector_type(8)));
typedef unsigned short us4 __attribute__((ext_vector_type(4)));
typedef unsigned int u32x4 __attribute__((ext_vector_type(4)));

__device__ __forceinline__ unsigned short f2bf(float x) {
  unsigned u = __builtin_bit_cast(unsigned, x);
  unsigned r = (u + 0x7fffu + ((u >> 16) & 1u)) >> 16;
  return (unsigned short)r;
}
__device__ __forceinline__ unsigned pack2bf(float a, float b) {
  return (unsigned)f2bf(a) | ((unsigned)f2bf(b) << 16);
}
__device__ __forceinline__ unsigned long long pack4bf(float a, float b, float c, float d) {
  return (unsigned long long)pack2bf(a, b) | ((unsigned long long)pack2bf(c, d) << 32);
}
__device__ __forceinline__ float ubf(unsigned short u) {
  return __builtin_bit_cast(float, (unsigned)u << 16);
}

// fragment-order index for a [128k x 128n] weight
__device__ __forceinline__ int fragidx(int k, int c) {
  int nf = c >> 4, lr = c & 15, ks = k >> 5, lq = (k >> 3) & 3, j = k & 7;
  return ((((nf << 2) + ks) << 6) | (lq << 4) | lr) * 8 + j;
}

// ---------------------------------------------------------------------------
// One-time weight conversion: [0]=W1a [1]=W1b [2]=W2 [3..5]=U1(0.5 on 1,2)
// [6]=U2  [7]=We (16x128 bf16 row-major, 2048 shorts)
// ---------------------------------------------------------------------------
__global__ __launch_bounds__(256) void prep_all(
    const float* __restrict__ mW1, const float* __restrict__ mW2,
    const float* __restrict__ uW1, const float* __restrict__ uW2,
    unsigned short* __restrict__ wfrag) {
  int b = blockIdx.x;
  if (b == 7) {
    const float* s7 = mW1 + 256 * 128;
    unsigned short* oc = wfrag + 7L * 16384;
    for (int i = threadIdx.x; i < 2048; i += 256) oc[i] = f2bf(s7[i]);
    return;
  }
  const float* src;
  float sc = 1.f;
  switch (b) {
    case 0: src = mW1; break;
    case 1: src = mW1 + 16384; break;
    case 2: src = mW2; break;
    case 3: src = uW1; break;
    case 4: src = uW1 + 16384; sc = 0.5f; break;
    case 5: src = uW1 + 32768; sc = 0.5f; break;
    default: src = uW2; break;
  }
  unsigned short* oc = wfrag + (long)b * 16384;
  for (int i = threadIdx.x; i < 16384; i += 256) {
    oc[fragidx(i >> 7, i & 127)] = f2bf(src[i] * sc);
  }
}

// ---------------------------------------------------------------------------
// Counting sort by src: hist -> 2-level exclusive scan -> permute.
// ---------------------------------------------------------------------------
__global__ __launch_bounds__(256) void hist_kernel(
    const int* __restrict__ SRC, long E, int* __restrict__ counts) {
  long i = (long)blockIdx.x * 256 + threadIdx.x;
  long str = (long)gridDim.x * 256;
  for (; i < E; i += str) atomicAdd(&counts[SRC[i]], 1);
}

__global__ __launch_bounds__(256) void scan1(
    const int* __restrict__ counts, int n, int* __restrict__ tmp,
    int* __restrict__ bsum) {
  __shared__ int sd[256];
  int b = blockIdx.x, tid = threadIdx.x;
  int base = b * 1024 + tid * 4;
  int c[4], t = 0;
  #pragma unroll
  for (int j = 0; j < 4; ++j) {
    int idx = base + j;
    c[j] = (idx < n) ? counts[idx] : 0;
    t += c[j];
  }
  sd[tid] = t;
  __syncthreads();
  for (int off = 1; off < 256; off <<= 1) {
    int v = (tid >= off) ? sd[tid - off] : 0;
    __syncthreads();
    sd[tid] += v;
    __syncthreads();
  }
  int run = sd[tid] - t;
  #pragma unroll
  for (int j = 0; j < 4; ++j) {
    int idx = base + j;
    if (idx < n) tmp[idx] = run;
    run += c[j];
  }
  if (tid == 255) bsum[b] = sd[255];
}

__global__ __launch_bounds__(256) void scan2(int* __restrict__ bsum, int nb) {
  __shared__ int sd[256];
  int tid = threadIdx.x;
  int v = (tid < nb) ? bsum[tid] : 0;
  sd[tid] = v;
  __syncthreads();
  for (int off = 1; off < 256; off <<= 1) {
    int x = (tid >= off) ? sd[tid - off] : 0;
    __syncthreads();
    sd[tid] += x;
    __syncthreads();
  }
  if (tid < nb) bsum[tid] = sd[tid] - v;
}

__global__ __launch_bounds__(256) void scan3(
    const int* __restrict__ tmp, const int* __restrict__ bsum, int n,
    int* __restrict__ cursor) {
  int i = blockIdx.x * 256 + threadIdx.x;
  if (i < n) cursor[i] = tmp[i] + bsum[i >> 10];
}

__global__ __launch_bounds__(256) void permute_edges(
    const int* __restrict__ SRC, const int* __restrict__ DST,
    const float* __restrict__ EA, long E, int* __restrict__ cursor,
    int* __restrict__ sS, int* __restrict__ sD,
    unsigned short* __restrict__ EAb) {
  long i = (long)blockIdx.x * 256 + threadIdx.x;
  long str = (long)gridDim.x * 256;
  for (; i < E; i += str) {
    int s = SRC[i];
    int pos = atomicAdd(&cursor[s], 1);
    sS[pos] = s;
    sD[pos] = DST[i];
    const float4* ep = (const float4*)(EA + i * 16);
    float4 a = ep[0], b = ep[1], c = ep[2], d = ep[3];
    u32x4 lo, hi;
    lo[0] = pack2bf(a.x, a.y); lo[1] = pack2bf(a.z, a.w);
    lo[2] = pack2bf(b.x, b.y); lo[3] = pack2bf(b.z, b.w);
    hi[0] = pack2bf(c.x, c.y); hi[1] = pack2bf(c.z, c.w);
    hi[2] = pack2bf(d.x, d.y); hi[3] = pack2bf(d.z, d.w);
    *(u32x4*)(EAb + (long)pos * 16) = lo;
    *(u32x4*)(EAb + (long)pos * 16 + 8) = hi;
  }
}

// ---------------------------------------------------------------------------
// Merged node GEMM: emits interleaved bf16 [P|Q] rows (256 shorts/node).
// ---------------------------------------------------------------------------
__global__ __launch_bounds__(256) void node_mfma_pq(
    const float* __restrict__ h, const unsigned short* __restrict__ WfA,
    unsigned short* __restrict__ pqb, int n) {
  __shared__ unsigned short WT[16384];
  int tid = threadIdx.x;
  int lid = tid & 63, w = tid >> 6, lr = lid & 15, lq = lid >> 4;
  long rbase = (long)blockIdx.x * 64 + 16 * w;
  long r = rbase + lr;
  bool rv = (r < n);
  long rl = rv ? r : 0;
  const us8* WF8 = (const us8*)WT;

  bf16x8 af[4];
  const float* Ar = h + rl * 128;
  #pragma unroll
  for (int ks = 0; ks < 4; ++ks) {
    int e0 = 32 * ks + 8 * lq;
    float4 x = *(const float4*)(Ar + e0);
    float4 y = *(const float4*)(Ar + e0 + 4);
    u32x4 t;
    t[0] = pack2bf(x.x, x.y); t[1] = pack2bf(x.z, x.w);
    t[2] = pack2bf(y.x, y.y); t[3] = pack2bf(y.z, y.w);
    if (!rv) { t[0] = 0; t[1] = 0; t[2] = 0; t[3] = 0; }
    af[ks] = __builtin_bit_cast(bf16x8, t);
  }

  f32x4 accP[8], accQ[8];
  #pragma unroll
  for (int nf = 0; nf < 8; ++nf) {
    accP[nf] = f32x4{0.f, 0.f, 0.f, 0.f};
    accQ[nf] = f32x4{0.f, 0.f, 0.f, 0.f};
  }

  for (int i = tid; i < 2048; i += 256) ((us8*)WT)[i] = ((const us8*)WfA)[i];
  __syncthreads();
  #pragma unroll
  for (int nf = 0; nf < 8; ++nf) {
    #pragma unroll
    for (int ks = 0; ks < 4; ++ks) {
      bf16x8 bf = __builtin_bit_cast(bf16x8, WF8[(nf * 4 + ks) * 64 + lid]);
      accP[nf] = __builtin_amdgcn_mfma_f32_16x16x32_bf16(af[ks], bf, accP[nf], 0, 0, 0);
    }
  }
  __syncthreads();
  for (int i = tid; i < 2048; i += 256) ((us8*)WT)[i] = ((const us8*)(WfA + 16384))[i];
  __syncthreads();
  #pragma unroll
  for (int nf = 0; nf < 8; ++nf) {
    #pragma unroll
    for (int ks = 0; ks < 4; ++ks) {
      bf16x8 bf = __builtin_bit_cast(bf16x8, WF8[(nf * 4 + ks) * 64 + lid]);
      accQ[nf] = __builtin_amdgcn_mfma_f32_16x16x32_bf16(af[ks], bf, accQ[nf], 0, 0, 0);
    }
  }

  #pragma unroll
  for (int nf = 0; nf < 8; ++nf) {
    #pragma unroll
    for (int i = 0; i < 4; ++i) {
      long nd = rbase + 4 * lq + i;
      if (nd < n) {
        int ch = 16 * nf + lr;
        pqb[nd * 256 + ch] = f2bf(accP[nf][i]);
        pqb[nd * 256 + 128 + ch] = f2bf(accQ[nf][i]);
      }
    }
  }
}

// ---------------------------------------------------------------------------
// General node MFMA GEMM (nk chunks, frag-order weights) with stats.
// ---------------------------------------------------------------------------
template <bool ABF16>
__global__ __launch_bounds__(256) void node_mfma(
    const void* A0, const void* A1, const void* A2,
    const unsigned short* __restrict__ Wf,
    float* __restrict__ C, int n, int dostats,
    float* __restrict__ sum_out, float* __restrict__ ssq_out, int nk) {
  __shared__ unsigned short WT[16384];
  int tid = threadIdx.x;
  int lid = tid & 63, w = tid >> 6, lr = lid & 15, lq = lid >> 4;
  long rbase = (long)blockIdx.x * 64 + 16 * w;

  const void* As[3] = {A0, A1, A2};
  f32x4 acc[8];
  #pragma unroll
  for (int nf = 0; nf < 8; ++nf) acc[nf] = f32x4{0.f, 0.f, 0.f, 0.f};

  long r = rbase + lr;
  bool rv = (r < n);
  long rl = rv ? r : 0;
  const us8* WF8 = (const us8*)WT;

  for (int c = 0; c < nk; ++c) {
    if (c) __syncthreads();
    const us8* src = (const us8*)(Wf + (long)c * 16384);
    for (int i = tid; i < 2048; i += 256) ((us8*)WT)[i] = src[i];
    __syncthreads();

    bf16x8 af[4];
    if (ABF16) {
      const us8* Ar = (const us8*)((const unsigned short*)As[c] + rl * 128);
      #pragma unroll
      for (int ks = 0; ks < 4; ++ks) {
        us8 v = Ar[ks * 4 + lq];
        if (!rv) v = us8{0, 0, 0, 0, 0, 0, 0, 0};
        af[ks] = __builtin_bit_cast(bf16x8, v);
      }
    } else {
      const float* Ar = (const float*)As[c] + rl * 128;
      #pragma unroll
      for (int ks = 0; ks < 4; ++ks) {
        int e0 = 32 * ks + 8 * lq;
        float4 x = *(const float4*)(Ar + e0);
        float4 y = *(const float4*)(Ar + e0 + 4);
        u32x4 t;
        t[0] = pack2bf(x.x, x.y); t[1] = pack2bf(x.z, x.w);
        t[2] = pack2bf(y.x, y.y); t[3] = pack2bf(y.z, y.w);
        if (!rv) { t[0] = 0; t[1] = 0; t[2] = 0; t[3] = 0; }
        af[ks] = __builtin_bit_cast(bf16x8, t);
      }
    }
    #pragma unroll
    for (int nf = 0; nf < 8; ++nf) {
      #pragma unroll
      for (int ks = 0; ks < 4; ++ks) {
        bf16x8 bf = __builtin_bit_cast(bf16x8, WF8[(nf * 4 + ks) * 64 + lid]);
        acc[nf] = __builtin_amdgcn_mfma_f32_16x16x32_bf16(af[ks], bf, acc[nf], 0, 0, 0);
      }
    }
  }

  float lsum[8], lssq[8];
  #pragma unroll
  for (int nf = 0; nf < 8; ++nf) { lsum[nf] = 0.f; lssq[nf] = 0.f; }
  #pragma unroll
  for (int nf = 0; nf < 8; ++nf) {
    #pragma unroll
    for (int i = 0; i < 4; ++i) {
      long nd = rbase + 4 * lq + i;
      if (nd < n) {
        float v = acc[nf][i];
        C[nd * 128 + 16 * nf + lr] = v;
        lsum[nf] += v; lssq[nf] += v * v;
      }
    }
  }
  if (dostats) {
    #pragma unroll
    for (int nf = 0; nf < 8; ++nf) {
      float v0 = lsum[nf]; v0 += __shfl_xor(v0, 16); v0 += __shfl_xor(v0, 32);
      float v1 = lssq[nf]; v1 += __shfl_xor(v1, 16); v1 += __shfl_xor(v1, 32);
      if (lq == 0) {
        atomicAdd(&sum_out[16 * nf + lr], v0);
        atomicAdd(&ssq_out[16 * nf + lr], v1);
      }
    }
  }
}

// ---------------------------------------------------------------------------
// BN1 stats over sorted edges, bf16 PQ rows + bf16 ea.
// ---------------------------------------------------------------------------
__global__ __launch_bounds__(256) void msg_stats1b(
    const unsigned short* __restrict__ PQ,
    const unsigned short* __restrict__ EAb, const float* __restrict__ W1e,
    const int* __restrict__ SRC, const int* __restrict__ DST, long E,
    float* __restrict__ stats) {
  __shared__ float Wel[16][128];
  __shared__ float red[32][16];
  int tid = threadIdx.x;
  for (int i = tid; i < 16 * 128; i += 256) ((float*)Wel)[i] = W1e[i];
  for (int i = tid; i < 512; i += 256) ((float*)red)[i] = 0.f;
  __syncthreads();
  int c4 = tid & 31, grp = tid >> 5;
  float4 s_st = {0,0,0,0}, q_st = {0,0,0,0}, s_ts = {0,0,0,0}, q_ts = {0,0,0,0};
  long stride = (long)gridDim.x * 8;
  for (long e = (long)blockIdx.x * 8 + grp; e < E; e += stride) {
    int s = SRC[e], t = DST[e];
    const unsigned short* Rs = PQ + (long)s * 256;
    const unsigned short* Rt = PQ + (long)t * 256;
    us4 Ps = *(const us4*)(Rs + 4 * c4);
    us4 Qs = *(const us4*)(Rs + 128 + 4 * c4);
    us4 Pt = *(const us4*)(Rt + 4 * c4);
    us4 Qt = *(const us4*)(Rt + 128 + 4 * c4);
    us8 evlo = *(const us8*)(EAb + e * 16);
    us8 evhi = *(const us8*)(EAb + e * 16 + 8);
    float rx = 0.f, ry = 0.f, rz = 0.f, rw = 0.f;
    #pragma unroll
    for (int k = 0; k < 16; ++k) {
      float f = (k < 8) ? ubf(evlo[k & 7]) : ubf(evhi[k & 7]);
      const float4 w4 = *(const float4*)&Wel[k][c4 * 4];
      rx = fmaf(f, w4.x, rx); ry = fmaf(f, w4.y, ry);
      rz = fmaf(f, w4.z, rz); rw = fmaf(f, w4.w, rw);
    }
    float zx = ubf(Ps[0]) + ubf(Qt[0]) + rx, zy = ubf(Ps[1]) + ubf(Qt[1]) + ry;
    float zz = ubf(Ps[2]) + ubf(Qt[2]) + rz, zw = ubf(Ps[3]) + ubf(Qt[3]) + rw;
    s_st.x += zx; s_st.y += zy; s_st.z += zz; s_st.w += zw;
    q_st.x += zx * zx; q_st.y += zy * zy; q_st.z += zz * zz; q_st.w += zw * zw;
    float ux = ubf(Pt[0]) + ubf(Qs[0]) + rx, uy = ubf(Pt[1]) + ubf(Qs[1]) + ry;
    float uz = ubf(Pt[2]) + ubf(Qs[2]) + rz, uw = ubf(Pt[3]) + ubf(Qs[3]) + rw;
    s_ts.x += ux; s_ts.y += uy; s_ts.z += uz; s_ts.w += uw;
    q_ts.x += ux * ux; q_ts.y += uy * uy; q_ts.z += uz * uz; q_ts.w += uw * uw;
  }
  atomicAdd(&red[c4][0], s_st.x);  atomicAdd(&red[c4][1], s_st.y);
  atomicAdd(&red[c4][2], s_st.z);  atomicAdd(&red[c4][3], s_st.w);
  atomicAdd(&red[c4][4], q_st.x);  atomicAdd(&red[c4][5], q_st.y);
  atomicAdd(&red[c4][6], q_st.z);  atomicAdd(&red[c4][7], q_st.w);
  atomicAdd(&red[c4][8], s_ts.x);  atomicAdd(&red[c4][9], s_ts.y);
  atomicAdd(&red[c4][10], s_ts.z); atomicAdd(&red[c4][11], s_ts.w);
  atomicAdd(&red[c4][12], q_ts.x); atomicAdd(&red[c4][13], q_ts.y);
  atomicAdd(&red[c4][14], q_ts.z); atomicAdd(&red[c4][15], q_ts.w);
  __syncthreads();
  #pragma unroll
  for (int rep = 0; rep < 2; ++rep) {
    int j = rep * 256 + tid;
    int cc = j >> 4, k = j & 15, group = k >> 2, comp = k & 3;
    atomicAdd(&stats[group * 128 + cc * 4 + comp], red[cc][k]);
  }
}

// ---------------------------------------------------------------------------
// Edge MFMA pass v9: double-buffered A-tiles with B-then-A region order
// (phase B's MFMA stream issues first; phase A's gathers for tile t+1 issue
// underneath it, hiding gather latency before the single barrier) + setprio
// around the MFMA cluster + cross-lane uniform-src atomic merge.
// LDS = 32KB W2F + 34.8KB dual A-tiles -> 2 blocks/CU.
// ---------------------------------------------------------------------------
template <bool SCATTER>
__global__ __launch_bounds__(256) void msg_mfma9(
    const unsigned short* __restrict__ PQ,
    const unsigned short* __restrict__ EAb,
    const unsigned short* __restrict__ Web,
    const unsigned short* __restrict__ W2f,
    const int* __restrict__ SRC, const int* __restrict__ DST, long E,
    const float* __restrict__ sc1, const float* __restrict__ sc2,
    float* __restrict__ stats2,
    float* __restrict__ a_st, float* __restrict__ a_ts) {
  __shared__ unsigned short W2F[16384];
  __shared__ unsigned short Atile[2][2][32][136];
  __shared__ int sArr[2][32];

  int tid = threadIdx.x;
  int c4 = tid & 31;      // phase-A channel quad
  int slot = tid >> 5;    // 0..7 edge slot
  int lid = tid & 63, w = tid >> 6, lr = lid & 15, lq = lid >> 4;
  int dir = w >> 1;       // 0 = st, 1 = ts
  int half = (w & 1) * 16;

  for (int i = tid; i < 2048; i += 256) ((us8*)W2F)[i] = ((const us8*)W2f)[i];
  const us8* W2F8 = (const us8*)W2F;

  // hoisted bf16 We slice for this thread's 4 channels
  us4 wreg[16];
  #pragma unroll
  for (int k = 0; k < 16; ++k) wreg[k] = *(const us4*)(Web + k * 128 + c4 * 4);

  const float4* sc1v = (const float4*)sc1;
  float4 scst = sc1v[c4], shst = sc1v[32 + c4];
  float4 scts = sc1v[64 + c4], shts = sc1v[96 + c4];

  float s2[8], h2[8];
  float ssum[8], sssq[8];
  if constexpr (SCATTER) {
    const float* scd = sc2 + dir * 256;
    #pragma unroll
    for (int nf = 0; nf < 8; ++nf) {
      int ch = 16 * nf + lr;
      s2[nf] = scd[ch]; h2[nf] = scd[128 + ch];
    }
  } else {
    #pragma unroll
    for (int nf = 0; nf < 8; ++nf) { ssum[nf] = 0.f; sssq[nf] = 0.f; }
  }
  float* accOut = dir ? a_ts : a_st;

  long tb0 = (long)blockIdx.x * 32;
  long tstep = (long)gridDim.x * 32;

  auto phaseA = [&](long tb, int p) {
    int nE = (int)(E - tb < 32 ? E - tb : 32);
    #pragma unroll
    for (int rep = 0; rep < 4; ++rep) {
      int er = rep * 8 + slot;
      if (er < nE) {
        long e = tb + er;
        int s = SRC[e], t = DST[e];
        if (SCATTER && c4 == 0) sArr[p][er] = s;
        const us4* Rs = (const us4*)(PQ + (long)s * 256);
        const us4* Rt = (const us4*)(PQ + (long)t * 256);
        us4 Ps = Rs[c4];
        us4 Qs = Rs[32 + c4];
        us4 Pt = Rt[c4];
        us4 Qt = Rt[32 + c4];
        us8 evlo = *(const us8*)(EAb + e * 16);
        us8 evhi = *(const us8*)(EAb + e * 16 + 8);
        float rx = 0.f, ry = 0.f, rz = 0.f, rw = 0.f;
        #pragma unroll
        for (int k = 0; k < 16; ++k) {
          float f = (k < 8) ? ubf(evlo[k & 7]) : ubf(evhi[k & 7]);
          rx = fmaf(f, ubf(wreg[k][0]), rx);
          ry = fmaf(f, ubf(wreg[k][1]), ry);
          rz = fmaf(f, ubf(wreg[k][2]), rz);
          rw = fmaf(f, ubf(wreg[k][3]), rw);
        }
        float ax = fmaxf(fmaf(ubf(Ps[0]) + ubf(Qt[0]) + rx, scst.x, shst.x), 0.f);
        float ay = fmaxf(fmaf(ubf(Ps[1]) + ubf(Qt[1]) + ry, scst.y, shst.y), 0.f);
        float az = fmaxf(fmaf(ubf(Ps[2]) + ubf(Qt[2]) + rz, scst.z, shst.z), 0.f);
        float aw = fmaxf(fmaf(ubf(Ps[3]) + ubf(Qt[3]) + rw, scst.w, shst.w), 0.f);
        *(unsigned long long*)&Atile[p][0][er][c4 * 4] = pack4bf(ax, ay, az, aw);
        float bx = fmaxf(fmaf(ubf(Pt[0]) + ubf(Qs[0]) + rx, scts.x, shts.x), 0.f);
        float by = fmaxf(fmaf(ubf(Pt[1]) + ubf(Qs[1]) + ry, scts.y, shts.y), 0.f);
        float bz = fmaxf(fmaf(ubf(Pt[2]) + ubf(Qs[2]) + rz, scts.z, shts.z), 0.f);
        float bw = fmaxf(fmaf(ubf(Pt[3]) + ubf(Qs[3]) + rw, scts.w, shts.w), 0.f);
        *(unsigned long long*)&Atile[p][1][er][c4 * 4] = pack4bf(bx, by, bz, bw);
      } else {
        *(unsigned long long*)&Atile[p][0][er][c4 * 4] = 0ull;
        *(unsigned long long*)&Atile[p][1][er][c4 * 4] = 0ull;
      }
    }
  };

  // prologue
  if (tb0 < E) phaseA(tb0, 0);
  __syncthreads();

  int p = 0;
  for (long tb = tb0; tb < E; tb += tstep) {
    int nE = (int)(E - tb < 32 ? E - tb : 32);
    long tnext = tb + tstep;

    // ---- phase B FIRST: MFMA from buf p (no global-latency dependency) ----
    int arow = half + lr;
    const char* ap = (const char*)&Atile[p][dir][arow][0];
    int acolb = lq * 16;
    bf16x8 af[4];
    #pragma unroll
    for (int ks = 0; ks < 4; ++ks) {
      af[ks] = *(const bf16x8*)(ap + ks * 64 + acolb);
    }
    int srow[4];
    bool uniform = false;
    int usrc = -1;
    if constexpr (SCATTER) {
      #pragma unroll
      for (int i = 0; i < 4; ++i) {
        int row = half + 4 * lq + i;
        srow[i] = (row < nE) ? sArr[p][row] : -1;
      }
      if (half + 15 < nE) {
        usrc = sArr[p][half];
        uniform = (usrc == sArr[p][half + 15]);
      }
    }
    f32x4 acc[8];
    __builtin_amdgcn_s_setprio(1);
    #pragma unroll
    for (int nf = 0; nf < 8; ++nf) {
      acc[nf] = f32x4{0.f, 0.f, 0.f, 0.f};
      #pragma unroll
      for (int ks = 0; ks < 4; ++ks) {
        bf16x8 bf = __builtin_bit_cast(bf16x8, W2F8[(nf * 4 + ks) * 64 + lid]);
        acc[nf] = __builtin_amdgcn_mfma_f32_16x16x32_bf16(af[ks], bf, acc[nf], 0, 0, 0);
      }
    }
    __builtin_amdgcn_s_setprio(0);

    // ---- phase A for next tile (gathers issue under the MFMA stream) ----
    if (tnext < E) phaseA(tnext, p ^ 1);

    // ---- epilogue of phase B: stats or scatter ----
    #pragma unroll
    for (int nf = 0; nf < 8; ++nf) {
      if constexpr (SCATTER) {
        int ch = 16 * nf + lr;
        if (uniform) {
          float m = 0.f;
          #pragma unroll
          for (int i = 0; i < 4; ++i)
            m += fmaxf(fmaf(acc[nf][i], s2[nf], h2[nf]), 0.f);
          m += __shfl_xor(m, 16);
          m += __shfl_xor(m, 32);
          if (lq == 0 && m != 0.f)
            atomicAdd(&accOut[(long)usrc * 128 + ch], m);
        } else {
          int cur = srow[0];
          float m = fmaxf(fmaf(acc[nf][0], s2[nf], h2[nf]), 0.f);
          #pragma unroll
          for (int i = 1; i < 4; ++i) {
            float v = fmaxf(fmaf(acc[nf][i], s2[nf], h2[nf]), 0.f);
            if (srow[i] == cur) {
              m += v;
            } else {
              if (cur >= 0 && m != 0.f) atomicAdd(&accOut[(long)cur * 128 + ch], m);
              cur = srow[i]; m = v;
            }
          }
          if (cur >= 0 && m != 0.f) atomicAdd(&accOut[(long)cur * 128 + ch], m);
        }
      } else {
        #pragma unroll
        for (int i = 0; i < 4; ++i) {
          ssum[nf] += acc[nf][i]; sssq[nf] += acc[nf][i] * acc[nf][i];
        }
      }
    }
    __syncthreads();
    p ^= 1;
  }

  if constexpr (!SCATTER) {
    #pragma unroll
    for (int nf = 0; nf < 8; ++nf) {
      float v0 = ssum[nf]; v0 += __shfl_xor(v0, 16); v0 += __shfl_xor(v0, 32);
      float v1 = sssq[nf]; v1 += __shfl_xor(v1, 16); v1 += __shfl_xor(v1, 32);
      if (lq == 0) {
        int ch = 16 * nf + lr;
        atomicAdd(&stats2[dir * 256 + ch], v0);
        atomicAdd(&stats2[dir * 256 + 128 + ch], v1);
      }
    }
  }
}

__global__ void bn_finalize(const float* __restrict__ sum, const float* __restrict__ ssq,
                            float invN, const float* __restrict__ g,
                            const float* __restrict__ be,
                            float* __restrict__ sc, float* __restrict__ sh) {
  int j = threadIdx.x;
  float m = sum[j] * invN;
  float v = ssq[j] * invN - m * m;
  float s = g[j] * rsqrtf(v + EPS_BN);
  sc[j] = s;
  sh[j] = be[j] - m * s;
}

__global__ __launch_bounds__(256) void prescale_relu(
    const float* __restrict__ X, const float* __restrict__ scsh,
    unsigned* __restrict__ out, long nrows) {
  long gid = (long)blockIdx.x * 256 + threadIdx.x;
  int c2 = (int)(gid & 63);
  float s0 = scsh[2 * c2], s1 = scsh[2 * c2 + 1];
  float h0 = scsh[128 + 2 * c2], h1 = scsh[128 + 2 * c2 + 1];
  const float2* X2 = (const float2*)X;
  long rstride = ((long)gridDim.x * 256) >> 6;
  for (long row = gid >> 6; row < nrows; row += rstride) {
    float2 x = X2[row * 64 + c2];
    out[row * 64 + c2] = pack2bf(fmaxf(fmaf(x.x, s0, h0), 0.f),
                                 fmaxf(fmaf(x.y, s1, h1), 0.f));
  }
}

__global__ __launch_bounds__(256) void bn_relu_out(
    const float* __restrict__ U2, const float* __restrict__ scsh,
    float* __restrict__ out, long total) {
  long i = (long)blockIdx.x * blockDim.x + threadIdx.x;
  long stride = (long)gridDim.x * blockDim.x;
  for (; i < total; i += stride) {
    int j = (int)(i & 127);
    out[i] = fmaxf(fmaf(U2[i], scsh[j], scsh[128 + j]), 0.f);
  }
}

extern "C" void kernel_launch(void* const* d_in, const int* in_sizes, int n_in,
                              void* d_out, int out_size, void* d_ws, size_t ws_size,
                              hipStream_t stream) {
  const float* h    = (const float*)d_in[0];
  const int*   ei   = (const int*)d_in[1];
  const float* ea   = (const float*)d_in[2];
  const float* mW1  = (const float*)d_in[3];
  const float* mg1  = (const float*)d_in[5];
  const float* mbe1 = (const float*)d_in[6];
  const float* mW2  = (const float*)d_in[7];
  const float* mg2  = (const float*)d_in[9];
  const float* mbe2 = (const float*)d_in[10];
  const float* uW1  = (const float*)d_in[11];
  const float* ug1  = (const float*)d_in[13];
  const float* ube1 = (const float*)d_in[14];
  const float* uW2  = (const float*)d_in[15];
  const float* ug2  = (const float*)d_in[17];
  const float* ube2 = (const float*)d_in[18];

  int n = in_sizes[0] / 128;
  long E = (long)(in_sizes[1] / 2);
  const int* SRC = ei;
  const int* DST = ei + E;
  const float* W1e = mW1 + 256 * 128;

  size_t nf = (size_t)n * 128;
  unsigned short* pqb = (unsigned short*)d_ws;
  float* a_st = (float*)(pqb + (size_t)n * 256);
  float* a_ts = a_st + nf;
  float* st   = a_ts + nf;
  unsigned short* wfrag = (unsigned short*)(st + 3072);
  unsigned short* wfA  = wfrag;
  unsigned short* wfW2 = wfrag + 2 * 16384;
  unsigned short* wfU1 = wfrag + 3 * 16384;
  unsigned short* wfU2 = wfrag + 6 * 16384;
  unsigned short* wfWe = wfrag + 7 * 16384;        // 2048 shorts
  int* sS = (int*)(wfWe + 2048);
  int* sD = sS + E;
  unsigned short* EAb = (unsigned short*)(sD + E);
  int* counts = (int*)(EAb + (size_t)E * 16);
  int* tmp = counts + n;
  int* bsum = tmp + n;

  float invE = 1.0f / (float)E;
  float invN = 1.0f / (float)n;
  int nblk = (n + 63) / 64;
  int nb1 = (n + 1023) / 1024;

  prep_all<<<8, 256, 0, stream>>>(mW1, mW2, uW1, uW2, wfrag);
  hipMemsetAsync(st, 0, 3072 * sizeof(float), stream);
  hipMemsetAsync(a_st, 0, 2 * nf * sizeof(float), stream);
  hipMemsetAsync(counts, 0, (size_t)n * sizeof(int), stream);

  // counting sort by src
  hist_kernel<<<1024, 256, 0, stream>>>(SRC, E, counts);
  scan1<<<nb1, 256, 0, stream>>>(counts, n, tmp, bsum);
  scan2<<<1, 256, 0, stream>>>(bsum, nb1);
  scan3<<<(n + 255) / 256, 256, 0, stream>>>(tmp, bsum, n, counts);
  permute_edges<<<1024, 256, 0, stream>>>(SRC, DST, ea, E, counts, sS, sD, EAb);

  // interleaved bf16 [P|Q] rows
  node_mfma_pq<<<nblk, 256, 0, stream>>>(h, wfA, pqb, n);

  // BN1 stats (sorted edges)
  msg_stats1b<<<2048, 256, 0, stream>>>(pqb, EAb, W1e, sS, sD, E, st);
  bn_finalize<<<1, 128, 0, stream>>>(st + 0,   st + 128, invE, mg1, mbe1, st + 1536, st + 1664);
  bn_finalize<<<1, 128, 0, stream>>>(st + 256, st + 384, invE, mg1, mbe1, st + 1792, st + 1920);

  // BN2 stats
  msg_mfma9<false><<<1536, 256, 0, stream>>>(
      pqb, EAb, wfWe, wfW2, sS, sD, E, st + 1536, nullptr, st + 512, nullptr, nullptr);
  bn_finalize<<<1, 128, 0, stream>>>(st + 512, st + 640, invE, mg2, mbe2, st + 2048, st + 2176);
  bn_finalize<<<1, 128, 0, stream>>>(st + 768, st + 896, invE, mg2, mbe2, st + 2304, st + 2432);

  // recompute + BN2+ReLU + merged scatter
  msg_mfma9<true><<<1536, 256, 0, stream>>>(
      pqb, EAb, wfWe, wfW2, sS, sD, E, st + 1536, st + 2048, nullptr, a_st, a_ts);

  // u1 = h@uW1a + 0.5*a_st@uW1b + 0.5*a_ts@uW1c -> pqb region (fp32)
  float* u1 = (float*)pqb;
  node_mfma<false><<<nblk, 256, 0, stream>>>(h, a_st, a_ts, wfU1,
                                             u1, n, 1, st + 1024, st + 1152, 3);
  bn_finalize<<<1, 128, 0, stream>>>(st + 1024, st + 1152, invN, ug1, ube1, st + 2560, st + 2688);

  // u1p (bf16) -> a_st region ; u2 -> a_ts region
  unsigned short* u1p = (unsigned short*)a_st;
  float* u2 = a_ts;
  prescale_relu<<<2048, 256, 0, stream>>>(u1, st + 2560, (unsigned*)u1p, n);
  node_mfma<true><<<nblk, 256, 0, stream>>>(u1p, nullptr, nullptr, wfU2,
                                            u2, n, 1, st + 1280, st + 1408, 1);
  bn_finalize<<<1, 128, 0, stream>>>(st + 1280, st + 1408, invN, ug2, ube2, st + 2816, st + 2944);

  bn_relu_out<<<2048, 256, 0, stream>>>(u2, st + 2816, (float*)d_out, (long)n * 128);
}

// Round 18
// 2435.277 us; speedup vs baseline: 1.0162x; 1.0162x over previous
//
#include <hip/hip_runtime.h>

#define EPS_BN 1e-5f

typedef __bf16 bf16x8 __attribute__((ext_vector_type(8)));
typedef _Float16 h4 __attribute__((ext_vector_type(4)));
typedef _Float16 h8 __attribute__((ext_vector_type(8)));
typedef float f32x4 __attribute__((ext_vector_type(4)));
typedef unsigned short us8 __attribute__((ext_vector_type(8)));
typedef unsigned short us4 __attribute__((ext_vector_type(4)));
typedef unsigned int u32x4 __attribute__((ext_vector_type(4)));

__device__ __forceinline__ unsigned short f2bf(float x) {
  unsigned u = __builtin_bit_cast(unsigned, x);
  unsigned r = (u + 0x7fffu + ((u >> 16) & 1u)) >> 16;
  return (unsigned short)r;
}
__device__ __forceinline__ unsigned pack2bf(float a, float b) {
  return (unsigned)f2bf(a) | ((unsigned)f2bf(b) << 16);
}
__device__ __forceinline__ unsigned short f2h(float x) {
  return __builtin_bit_cast(unsigned short, (_Float16)x);
}
__device__ __forceinline__ unsigned pack2h(float a, float b) {
  return (unsigned)f2h(a) | ((unsigned)f2h(b) << 16);
}
__device__ __forceinline__ float ubf(unsigned short u) {
  return __builtin_bit_cast(float, (unsigned)u << 16);
}
__device__ __forceinline__ h4 relu4(h4 x) {
  h4 z = {(_Float16)0.f, (_Float16)0.f, (_Float16)0.f, (_Float16)0.f};
  return __builtin_elementwise_max(x, z);
}

// fragment-order index for a [128k x 128n] weight
__device__ __forceinline__ int fragidx(int k, int c) {
  int nf = c >> 4, lr = c & 15, ks = k >> 5, lq = (k >> 3) & 3, j = k & 7;
  return ((((nf << 2) + ks) << 6) | (lq << 4) | lr) * 8 + j;
}

// ---------------------------------------------------------------------------
// One-time weight conversion: [0]=W1a [1]=W1b [2]=W2(fp16) [3..5]=U1(0.5 on 1,2)
// [6]=U2  [7]=We (16x128 fp16 row-major, 2048 shorts)
// ---------------------------------------------------------------------------
__global__ __launch_bounds__(256) void prep_all(
    const float* __restrict__ mW1, const float* __restrict__ mW2,
    const float* __restrict__ uW1, const float* __restrict__ uW2,
    unsigned short* __restrict__ wfrag) {
  int b = blockIdx.x;
  if (b == 7) {
    const float* s7 = mW1 + 256 * 128;
    unsigned short* oc = wfrag + 7L * 16384;
    for (int i = threadIdx.x; i < 2048; i += 256) oc[i] = f2h(s7[i]);
    return;
  }
  const float* src;
  float sc = 1.f;
  switch (b) {
    case 0: src = mW1; break;
    case 1: src = mW1 + 16384; break;
    case 2: src = mW2; break;
    case 3: src = uW1; break;
    case 4: src = uW1 + 16384; sc = 0.5f; break;
    case 5: src = uW1 + 32768; sc = 0.5f; break;
    default: src = uW2; break;
  }
  unsigned short* oc = wfrag + (long)b * 16384;
  bool fp16 = (b == 2);
  for (int i = threadIdx.x; i < 16384; i += 256) {
    float v = src[i] * sc;
    oc[fragidx(i >> 7, i & 127)] = fp16 ? f2h(v) : f2bf(v);
  }
}

// ---------------------------------------------------------------------------
// Counting sort by src: hist -> 2-level exclusive scan -> permute.
// ---------------------------------------------------------------------------
__global__ __launch_bounds__(256) void hist_kernel(
    const int* __restrict__ SRC, long E, int* __restrict__ counts) {
  long i = (long)blockIdx.x * 256 + threadIdx.x;
  long str = (long)gridDim.x * 256;
  for (; i < E; i += str) atomicAdd(&counts[SRC[i]], 1);
}

__global__ __launch_bounds__(256) void scan1(
    const int* __restrict__ counts, int n, int* __restrict__ tmp,
    int* __restrict__ bsum) {
  __shared__ int sd[256];
  int b = blockIdx.x, tid = threadIdx.x;
  int base = b * 1024 + tid * 4;
  int c[4], t = 0;
  #pragma unroll
  for (int j = 0; j < 4; ++j) {
    int idx = base + j;
    c[j] = (idx < n) ? counts[idx] : 0;
    t += c[j];
  }
  sd[tid] = t;
  __syncthreads();
  for (int off = 1; off < 256; off <<= 1) {
    int v = (tid >= off) ? sd[tid - off] : 0;
    __syncthreads();
    sd[tid] += v;
    __syncthreads();
  }
  int run = sd[tid] - t;
  #pragma unroll
  for (int j = 0; j < 4; ++j) {
    int idx = base + j;
    if (idx < n) tmp[idx] = run;
    run += c[j];
  }
  if (tid == 255) bsum[b] = sd[255];
}

__global__ __launch_bounds__(256) void scan2(int* __restrict__ bsum, int nb) {
  __shared__ int sd[256];
  int tid = threadIdx.x;
  int v = (tid < nb) ? bsum[tid] : 0;
  sd[tid] = v;
  __syncthreads();
  for (int off = 1; off < 256; off <<= 1) {
    int x = (tid >= off) ? sd[tid - off] : 0;
    __syncthreads();
    sd[tid] += x;
    __syncthreads();
  }
  if (tid < nb) bsum[tid] = sd[tid] - v;
}

__global__ __launch_bounds__(256) void scan3(
    const int* __restrict__ tmp, const int* __restrict__ bsum, int n,
    int* __restrict__ cursor) {
  int i = blockIdx.x * 256 + threadIdx.x;
  if (i < n) cursor[i] = tmp[i] + bsum[i >> 10];
}

__global__ __launch_bounds__(256) void permute_edges(
    const int* __restrict__ SRC, const int* __restrict__ DST,
    const float* __restrict__ EA, long E, int* __restrict__ cursor,
    int* __restrict__ sS, int* __restrict__ sD,
    unsigned short* __restrict__ EAh) {
  long i = (long)blockIdx.x * 256 + threadIdx.x;
  long str = (long)gridDim.x * 256;
  for (; i < E; i += str) {
    int s = SRC[i];
    int pos = atomicAdd(&cursor[s], 1);
    sS[pos] = s;
    sD[pos] = DST[i];
    const float4* ep = (const float4*)(EA + i * 16);
    float4 a = ep[0], b = ep[1], c = ep[2], d = ep[3];
    u32x4 lo, hi;
    lo[0] = pack2h(a.x, a.y); lo[1] = pack2h(a.z, a.w);
    lo[2] = pack2h(b.x, b.y); lo[3] = pack2h(b.z, b.w);
    hi[0] = pack2h(c.x, c.y); hi[1] = pack2h(c.z, c.w);
    hi[2] = pack2h(d.x, d.y); hi[3] = pack2h(d.z, d.w);
    *(u32x4*)(EAh + (long)pos * 16) = lo;
    *(u32x4*)(EAh + (long)pos * 16 + 8) = hi;
  }
}

// ---------------------------------------------------------------------------
// Merged node GEMM: emits interleaved fp16 [P|Q] rows (256 shorts/node).
// ---------------------------------------------------------------------------
__global__ __launch_bounds__(256) void node_mfma_pq(
    const float* __restrict__ h, const unsigned short* __restrict__ WfA,
    unsigned short* __restrict__ pqb, int n) {
  __shared__ unsigned short WT[16384];
  int tid = threadIdx.x;
  int lid = tid & 63, w = tid >> 6, lr = lid & 15, lq = lid >> 4;
  long rbase = (long)blockIdx.x * 64 + 16 * w;
  long r = rbase + lr;
  bool rv = (r < n);
  long rl = rv ? r : 0;
  const us8* WF8 = (const us8*)WT;

  bf16x8 af[4];
  const float* Ar = h + rl * 128;
  #pragma unroll
  for (int ks = 0; ks < 4; ++ks) {
    int e0 = 32 * ks + 8 * lq;
    float4 x = *(const float4*)(Ar + e0);
    float4 y = *(const float4*)(Ar + e0 + 4);
    u32x4 t;
    t[0] = pack2bf(x.x, x.y); t[1] = pack2bf(x.z, x.w);
    t[2] = pack2bf(y.x, y.y); t[3] = pack2bf(y.z, y.w);
    if (!rv) { t[0] = 0; t[1] = 0; t[2] = 0; t[3] = 0; }
    af[ks] = __builtin_bit_cast(bf16x8, t);
  }

  f32x4 accP[8], accQ[8];
  #pragma unroll
  for (int nf = 0; nf < 8; ++nf) {
    accP[nf] = f32x4{0.f, 0.f, 0.f, 0.f};
    accQ[nf] = f32x4{0.f, 0.f, 0.f, 0.f};
  }

  for (int i = tid; i < 2048; i += 256) ((us8*)WT)[i] = ((const us8*)WfA)[i];
  __syncthreads();
  #pragma unroll
  for (int nf = 0; nf < 8; ++nf) {
    #pragma unroll
    for (int ks = 0; ks < 4; ++ks) {
      bf16x8 bf = __builtin_bit_cast(bf16x8, WF8[(nf * 4 + ks) * 64 + lid]);
      accP[nf] = __builtin_amdgcn_mfma_f32_16x16x32_bf16(af[ks], bf, accP[nf], 0, 0, 0);
    }
  }
  __syncthreads();
  for (int i = tid; i < 2048; i += 256) ((us8*)WT)[i] = ((const us8*)(WfA + 16384))[i];
  __syncthreads();
  #pragma unroll
  for (int nf = 0; nf < 8; ++nf) {
    #pragma unroll
    for (int ks = 0; ks < 4; ++ks) {
      bf16x8 bf = __builtin_bit_cast(bf16x8, WF8[(nf * 4 + ks) * 64 + lid]);
      accQ[nf] = __builtin_amdgcn_mfma_f32_16x16x32_bf16(af[ks], bf, accQ[nf], 0, 0, 0);
    }
  }

  #pragma unroll
  for (int nf = 0; nf < 8; ++nf) {
    #pragma unroll
    for (int i = 0; i < 4; ++i) {
      long nd = rbase + 4 * lq + i;
      if (nd < n) {
        int ch = 16 * nf + lr;
        pqb[nd * 256 + ch] = f2h(accP[nf][i]);
        pqb[nd * 256 + 128 + ch] = f2h(accQ[nf][i]);
      }
    }
  }
}

// ---------------------------------------------------------------------------
// General node MFMA GEMM (nk chunks, frag-order bf16 weights) with stats.
// ---------------------------------------------------------------------------
template <bool ABF16>
__global__ __launch_bounds__(256) void node_mfma(
    const void* A0, const void* A1, const void* A2,
    const unsigned short* __restrict__ Wf,
    float* __restrict__ C, int n, int dostats,
    float* __restrict__ sum_out, float* __restrict__ ssq_out, int nk) {
  __shared__ unsigned short WT[16384];
  int tid = threadIdx.x;
  int lid = tid & 63, w = tid >> 6, lr = lid & 15, lq = lid >> 4;
  long rbase = (long)blockIdx.x * 64 + 16 * w;

  const void* As[3] = {A0, A1, A2};
  f32x4 acc[8];
  #pragma unroll
  for (int nf = 0; nf < 8; ++nf) acc[nf] = f32x4{0.f, 0.f, 0.f, 0.f};

  long r = rbase + lr;
  bool rv = (r < n);
  long rl = rv ? r : 0;
  const us8* WF8 = (const us8*)WT;

  for (int c = 0; c < nk; ++c) {
    if (c) __syncthreads();
    const us8* src = (const us8*)(Wf + (long)c * 16384);
    for (int i = tid; i < 2048; i += 256) ((us8*)WT)[i] = src[i];
    __syncthreads();

    bf16x8 af[4];
    if (ABF16) {
      const us8* Ar = (const us8*)((const unsigned short*)As[c] + rl * 128);
      #pragma unroll
      for (int ks = 0; ks < 4; ++ks) {
        us8 v = Ar[ks * 4 + lq];
        if (!rv) v = us8{0, 0, 0, 0, 0, 0, 0, 0};
        af[ks] = __builtin_bit_cast(bf16x8, v);
      }
    } else {
      const float* Ar = (const float*)As[c] + rl * 128;
      #pragma unroll
      for (int ks = 0; ks < 4; ++ks) {
        int e0 = 32 * ks + 8 * lq;
        float4 x = *(const float4*)(Ar + e0);
        float4 y = *(const float4*)(Ar + e0 + 4);
        u32x4 t;
        t[0] = pack2bf(x.x, x.y); t[1] = pack2bf(x.z, x.w);
        t[2] = pack2bf(y.x, y.y); t[3] = pack2bf(y.z, y.w);
        if (!rv) { t[0] = 0; t[1] = 0; t[2] = 0; t[3] = 0; }
        af[ks] = __builtin_bit_cast(bf16x8, t);
      }
    }
    #pragma unroll
    for (int nf = 0; nf < 8; ++nf) {
      #pragma unroll
      for (int ks = 0; ks < 4; ++ks) {
        bf16x8 bf = __builtin_bit_cast(bf16x8, WF8[(nf * 4 + ks) * 64 + lid]);
        acc[nf] = __builtin_amdgcn_mfma_f32_16x16x32_bf16(af[ks], bf, acc[nf], 0, 0, 0);
      }
    }
  }

  float lsum[8], lssq[8];
  #pragma unroll
  for (int nf = 0; nf < 8; ++nf) { lsum[nf] = 0.f; lssq[nf] = 0.f; }
  #pragma unroll
  for (int nf = 0; nf < 8; ++nf) {
    #pragma unroll
    for (int i = 0; i < 4; ++i) {
      long nd = rbase + 4 * lq + i;
      if (nd < n) {
        float v = acc[nf][i];
        C[nd * 128 + 16 * nf + lr] = v;
        lsum[nf] += v; lssq[nf] += v * v;
      }
    }
  }
  if (dostats) {
    #pragma unroll
    for (int nf = 0; nf < 8; ++nf) {
      float v0 = lsum[nf]; v0 += __shfl_xor(v0, 16); v0 += __shfl_xor(v0, 32);
      float v1 = lssq[nf]; v1 += __shfl_xor(v1, 16); v1 += __shfl_xor(v1, 32);
      if (lq == 0) {
        atomicAdd(&sum_out[16 * nf + lr], v0);
        atomicAdd(&ssq_out[16 * nf + lr], v1);
      }
    }
  }
}

// ---------------------------------------------------------------------------
// BN1 stats over sorted edges, fp16 PQ rows + fp16 ea.
// ---------------------------------------------------------------------------
__global__ __launch_bounds__(256) void msg_stats1b(
    const unsigned short* __restrict__ PQ,
    const unsigned short* __restrict__ EAh, const float* __restrict__ W1e,
    const int* __restrict__ SRC, const int* __restrict__ DST, long E,
    float* __restrict__ stats) {
  __shared__ float Wel[16][128];
  __shared__ float red[32][16];
  int tid = threadIdx.x;
  for (int i = tid; i < 16 * 128; i += 256) ((float*)Wel)[i] = W1e[i];
  for (int i = tid; i < 512; i += 256) ((float*)red)[i] = 0.f;
  __syncthreads();
  int c4 = tid & 31, grp = tid >> 5;
  float4 s_st = {0,0,0,0}, q_st = {0,0,0,0}, s_ts = {0,0,0,0}, q_ts = {0,0,0,0};
  long stride = (long)gridDim.x * 8;
  for (long e = (long)blockIdx.x * 8 + grp; e < E; e += stride) {
    int s = SRC[e], t = DST[e];
    const unsigned short* Rs = PQ + (long)s * 256;
    const unsigned short* Rt = PQ + (long)t * 256;
    h4 Ps = __builtin_bit_cast(h4, *(const us4*)(Rs + 4 * c4));
    h4 Qs = __builtin_bit_cast(h4, *(const us4*)(Rs + 128 + 4 * c4));
    h4 Pt = __builtin_bit_cast(h4, *(const us4*)(Rt + 4 * c4));
    h4 Qt = __builtin_bit_cast(h4, *(const us4*)(Rt + 128 + 4 * c4));
    h8 elo = __builtin_bit_cast(h8, *(const us8*)(EAh + e * 16));
    h8 ehi = __builtin_bit_cast(h8, *(const us8*)(EAh + e * 16 + 8));
    float rx = 0.f, ry = 0.f, rz = 0.f, rw = 0.f;
    #pragma unroll
    for (int k = 0; k < 16; ++k) {
      float f = (k < 8) ? (float)elo[k & 7] : (float)ehi[k & 7];
      const float4 w4 = *(const float4*)&Wel[k][c4 * 4];
      rx = fmaf(f, w4.x, rx); ry = fmaf(f, w4.y, ry);
      rz = fmaf(f, w4.z, rz); rw = fmaf(f, w4.w, rw);
    }
    float zx = (float)Ps[0] + (float)Qt[0] + rx, zy = (float)Ps[1] + (float)Qt[1] + ry;
    float zz = (float)Ps[2] + (float)Qt[2] + rz, zw = (float)Ps[3] + (float)Qt[3] + rw;
    s_st.x += zx; s_st.y += zy; s_st.z += zz; s_st.w += zw;
    q_st.x += zx * zx; q_st.y += zy * zy; q_st.z += zz * zz; q_st.w += zw * zw;
    float ux = (float)Pt[0] + (float)Qs[0] + rx, uy = (float)Pt[1] + (float)Qs[1] + ry;
    float uz = (float)Pt[2] + (float)Qs[2] + rz, uw = (float)Pt[3] + (float)Qs[3] + rw;
    s_ts.x += ux; s_ts.y += uy; s_ts.z += uz; s_ts.w += uw;
    q_ts.x += ux * ux; q_ts.y += uy * uy; q_ts.z += uz * uz; q_ts.w += uw * uw;
  }
  atomicAdd(&red[c4][0], s_st.x);  atomicAdd(&red[c4][1], s_st.y);
  atomicAdd(&red[c4][2], s_st.z);  atomicAdd(&red[c4][3], s_st.w);
  atomicAdd(&red[c4][4], q_st.x);  atomicAdd(&red[c4][5], q_st.y);
  atomicAdd(&red[c4][6], q_st.z);  atomicAdd(&red[c4][7], q_st.w);
  atomicAdd(&red[c4][8], s_ts.x);  atomicAdd(&red[c4][9], s_ts.y);
  atomicAdd(&red[c4][10], s_ts.z); atomicAdd(&red[c4][11], s_ts.w);
  atomicAdd(&red[c4][12], q_ts.x); atomicAdd(&red[c4][13], q_ts.y);
  atomicAdd(&red[c4][14], q_ts.z); atomicAdd(&red[c4][15], q_ts.w);
  __syncthreads();
  #pragma unroll
  for (int rep = 0; rep < 2; ++rep) {
    int j = rep * 256 + tid;
    int cc = j >> 4, k = j & 15, group = k >> 2, comp = k & 3;
    atomicAdd(&stats[group * 128 + cc * 4 + comp], red[cc][k]);
  }
}

// ---------------------------------------------------------------------------
// Edge MFMA pass v10: fp16 packed phase A (v_pk_fma/add/max), f16 MFMA phase B,
// double-buffered A-tiles (one barrier/tile, B-then-A order), setprio,
// cross-lane uniform-src atomic merge. LDS ~66KB -> 2 blocks/CU.
// ---------------------------------------------------------------------------
template <bool SCATTER>
__global__ __launch_bounds__(256) void msg_mfma10(
    const unsigned short* __restrict__ PQ,
    const unsigned short* __restrict__ EAh,
    const unsigned short* __restrict__ Weh,
    const unsigned short* __restrict__ W2f,
    const int* __restrict__ SRC, const int* __restrict__ DST, long E,
    const float* __restrict__ sc1, const float* __restrict__ sc2,
    float* __restrict__ stats2,
    float* __restrict__ a_st, float* __restrict__ a_ts) {
  __shared__ unsigned short W2F[16384];
  __shared__ unsigned short Atile[2][2][32][136];
  __shared__ int sArr[2][32];

  int tid = threadIdx.x;
  int c4 = tid & 31;      // phase-A channel quad
  int slot = tid >> 5;    // 0..7 edge slot
  int lid = tid & 63, w = tid >> 6, lr = lid & 15, lq = lid >> 4;
  int dir = w >> 1;       // 0 = st, 1 = ts
  int half = (w & 1) * 16;

  for (int i = tid; i < 2048; i += 256) ((us8*)W2F)[i] = ((const us8*)W2f)[i];
  const us8* W2F8 = (const us8*)W2F;

  // hoisted fp16 We slice for this thread's 4 channels (h4 registers)
  h4 wreg[16];
  #pragma unroll
  for (int k = 0; k < 16; ++k)
    wreg[k] = __builtin_bit_cast(h4, *(const us4*)(Weh + k * 128 + c4 * 4));

  int ch0 = c4 * 4;
  h4 scst4 = {(_Float16)sc1[ch0], (_Float16)sc1[ch0 + 1],
              (_Float16)sc1[ch0 + 2], (_Float16)sc1[ch0 + 3]};
  h4 shst4 = {(_Float16)sc1[128 + ch0], (_Float16)sc1[128 + ch0 + 1],
              (_Float16)sc1[128 + ch0 + 2], (_Float16)sc1[128 + ch0 + 3]};
  h4 scts4 = {(_Float16)sc1[256 + ch0], (_Float16)sc1[256 + ch0 + 1],
              (_Float16)sc1[256 + ch0 + 2], (_Float16)sc1[256 + ch0 + 3]};
  h4 shts4 = {(_Float16)sc1[384 + ch0], (_Float16)sc1[384 + ch0 + 1],
              (_Float16)sc1[384 + ch0 + 2], (_Float16)sc1[384 + ch0 + 3]};

  float s2[8], h2p[8];
  float ssum[8], sssq[8];
  if constexpr (SCATTER) {
    const float* scd = sc2 + dir * 256;
    #pragma unroll
    for (int nf = 0; nf < 8; ++nf) {
      int ch = 16 * nf + lr;
      s2[nf] = scd[ch]; h2p[nf] = scd[128 + ch];
    }
  } else {
    #pragma unroll
    for (int nf = 0; nf < 8; ++nf) { ssum[nf] = 0.f; sssq[nf] = 0.f; }
  }
  float* accOut = dir ? a_ts : a_st;

  long tb0 = (long)blockIdx.x * 32;
  long tstep = (long)gridDim.x * 32;

  auto phaseA = [&](long tb, int p) {
    int nE = (int)(E - tb < 32 ? E - tb : 32);
    #pragma unroll
    for (int rep = 0; rep < 4; ++rep) {
      int er = rep * 8 + slot;
      if (er < nE) {
        long e = tb + er;
        int s = SRC[e], t = DST[e];
        if (SCATTER && c4 == 0) sArr[p][er] = s;
        const us4* Rs = (const us4*)(PQ + (long)s * 256);
        const us4* Rt = (const us4*)(PQ + (long)t * 256);
        h4 Ps = __builtin_bit_cast(h4, Rs[c4]);
        h4 Qs = __builtin_bit_cast(h4, Rs[32 + c4]);
        h4 Pt = __builtin_bit_cast(h4, Rt[c4]);
        h4 Qt = __builtin_bit_cast(h4, Rt[32 + c4]);
        h8 elo = __builtin_bit_cast(h8, *(const us8*)(EAh + e * 16));
        h8 ehi = __builtin_bit_cast(h8, *(const us8*)(EAh + e * 16 + 8));
        h4 r = {(_Float16)0.f, (_Float16)0.f, (_Float16)0.f, (_Float16)0.f};
        #pragma unroll
        for (int k = 0; k < 16; ++k) {
          _Float16 f = (k < 8) ? elo[k & 7] : ehi[k & 7];
          h4 fv = {f, f, f, f};
          r += fv * wreg[k];
        }
        h4 zst = relu4((Ps + Qt + r) * scst4 + shst4);
        h4 zts = relu4((Pt + Qs + r) * scts4 + shts4);
        *(unsigned long long*)&Atile[p][0][er][ch0] =
            __builtin_bit_cast(unsigned long long, zst);
        *(unsigned long long*)&Atile[p][1][er][ch0] =
            __builtin_bit_cast(unsigned long long, zts);
      } else {
        *(unsigned long long*)&Atile[p][0][er][ch0] = 0ull;
        *(unsigned long long*)&Atile[p][1][er][ch0] = 0ull;
      }
    }
  };

  // prologue
  if (tb0 < E) phaseA(tb0, 0);
  __syncthreads();

  int p = 0;
  for (long tb = tb0; tb < E; tb += tstep) {
    int nE = (int)(E - tb < 32 ? E - tb : 32);
    long tnext = tb + tstep;

    // ---- phase B FIRST: f16 MFMA from buf p ----
    int arow = half + lr;
    const char* ap = (const char*)&Atile[p][dir][arow][0];
    int acolb = lq * 16;
    h8 af[4];
    #pragma unroll
    for (int ks = 0; ks < 4; ++ks) {
      af[ks] = *(const h8*)(ap + ks * 64 + acolb);
    }
    int srow[4];
    bool uniform = false;
    int usrc = -1;
    if constexpr (SCATTER) {
      #pragma unroll
      for (int i = 0; i < 4; ++i) {
        int row = half + 4 * lq + i;
        srow[i] = (row < nE) ? sArr[p][row] : -1;
      }
      if (half + 15 < nE) {
        usrc = sArr[p][half];
        uniform = (usrc == sArr[p][half + 15]);
      }
    }
    f32x4 acc[8];
    __builtin_amdgcn_s_setprio(1);
    #pragma unroll
    for (int nf = 0; nf < 8; ++nf) {
      acc[nf] = f32x4{0.f, 0.f, 0.f, 0.f};
      #pragma unroll
      for (int ks = 0; ks < 4; ++ks) {
        h8 bf = __builtin_bit_cast(h8, W2F8[(nf * 4 + ks) * 64 + lid]);
        acc[nf] = __builtin_amdgcn_mfma_f32_16x16x32_f16(af[ks], bf, acc[nf], 0, 0, 0);
      }
    }
    __builtin_amdgcn_s_setprio(0);

    // ---- phase A for next tile (gathers issue under the MFMA stream) ----
    if (tnext < E) phaseA(tnext, p ^ 1);

    // ---- epilogue of phase B: stats or scatter ----
    #pragma unroll
    for (int nf = 0; nf < 8; ++nf) {
      if constexpr (SCATTER) {
        int ch = 16 * nf + lr;
        if (uniform) {
          float m = 0.f;
          #pragma unroll
          for (int i = 0; i < 4; ++i)
            m += fmaxf(fmaf(acc[nf][i], s2[nf], h2p[nf]), 0.f);
          m += __shfl_xor(m, 16);
          m += __shfl_xor(m, 32);
          if (lq == 0 && m != 0.f)
            atomicAdd(&accOut[(long)usrc * 128 + ch], m);
        } else {
          int cur = srow[0];
          float m = fmaxf(fmaf(acc[nf][0], s2[nf], h2p[nf]), 0.f);
          #pragma unroll
          for (int i = 1; i < 4; ++i) {
            float v = fmaxf(fmaf(acc[nf][i], s2[nf], h2p[nf]), 0.f);
            if (srow[i] == cur) {
              m += v;
            } else {
              if (cur >= 0 && m != 0.f) atomicAdd(&accOut[(long)cur * 128 + ch], m);
              cur = srow[i]; m = v;
            }
          }
          if (cur >= 0 && m != 0.f) atomicAdd(&accOut[(long)cur * 128 + ch], m);
        }
      } else {
        #pragma unroll
        for (int i = 0; i < 4; ++i) {
          ssum[nf] += acc[nf][i]; sssq[nf] += acc[nf][i] * acc[nf][i];
        }
      }
    }
    __syncthreads();
    p ^= 1;
  }

  if constexpr (!SCATTER) {
    #pragma unroll
    for (int nf = 0; nf < 8; ++nf) {
      float v0 = ssum[nf]; v0 += __shfl_xor(v0, 16); v0 += __shfl_xor(v0, 32);
      float v1 = sssq[nf]; v1 += __shfl_xor(v1, 16); v1 += __shfl_xor(v1, 32);
      if (lq == 0) {
        int ch = 16 * nf + lr;
        atomicAdd(&stats2[dir * 256 + ch], v0);
        atomicAdd(&stats2[dir * 256 + 128 + ch], v1);
      }
    }
  }
}

__global__ void bn_finalize(const float* __restrict__ sum, const float* __restrict__ ssq,
                            float invN, const float* __restrict__ g,
                            const float* __restrict__ be,
                            float* __restrict__ sc, float* __restrict__ sh) {
  int j = threadIdx.x;
  float m = sum[j] * invN;
  float v = ssq[j] * invN - m * m;
  float s = g[j] * rsqrtf(v + EPS_BN);
  sc[j] = s;
  sh[j] = be[j] - m * s;
}

__global__ __launch_bounds__(256) void prescale_relu(
    const float* __restrict__ X, const float* __restrict__ scsh,
    unsigned* __restrict__ out, long nrows) {
  long gid = (long)blockIdx.x * 256 + threadIdx.x;
  int c2 = (int)(gid & 63);
  float s0 = scsh[2 * c2], s1 = scsh[2 * c2 + 1];
  float h0 = scsh[128 + 2 * c2], h1 = scsh[128 + 2 * c2 + 1];
  const float2* X2 = (const float2*)X;
  long rstride = ((long)gridDim.x * 256) >> 6;
  for (long row = gid >> 6; row < nrows; row += rstride) {
    float2 x = X2[row * 64 + c2];
    out[row * 64 + c2] = pack2bf(fmaxf(fmaf(x.x, s0, h0), 0.f),
                                 fmaxf(fmaf(x.y, s1, h1), 0.f));
  }
}

__global__ __launch_bounds__(256) void bn_relu_out(
    const float* __restrict__ U2, const float* __restrict__ scsh,
    float* __restrict__ out, long total) {
  long i = (long)blockIdx.x * blockDim.x + threadIdx.x;
  long stride = (long)gridDim.x * blockDim.x;
  for (; i < total; i += stride) {
    int j = (int)(i & 127);
    out[i] = fmaxf(fmaf(U2[i], scsh[j], scsh[128 + j]), 0.f);
  }
}

extern "C" void kernel_launch(void* const* d_in, const int* in_sizes, int n_in,
                              void* d_out, int out_size, void* d_ws, size_t ws_size,
                              hipStream_t stream) {
  const float* h    = (const float*)d_in[0];
  const int*   ei   = (const int*)d_in[1];
  const float* ea   = (const float*)d_in[2];
  const float* mW1  = (const float*)d_in[3];
  const float* mg1  = (const float*)d_in[5];
  const float* mbe1 = (const float*)d_in[6];
  const float* mW2  = (const float*)d_in[7];
  const float* mg2  = (const float*)d_in[9];
  const float* mbe2 = (const float*)d_in[10];
  const float* uW1  = (const float*)d_in[11];
  const float* ug1  = (const float*)d_in[13];
  const float* ube1 = (const float*)d_in[14];
  const float* uW2  = (const float*)d_in[15];
  const float* ug2  = (const float*)d_in[17];
  const float* ube2 = (const float*)d_in[18];

  int n = in_sizes[0] / 128;
  long E = (long)(in_sizes[1] / 2);
  const int* SRC = ei;
  const int* DST = ei + E;
  const float* W1e = mW1 + 256 * 128;

  size_t nf = (size_t)n * 128;
  unsigned short* pqb = (unsigned short*)d_ws;
  float* a_st = (float*)(pqb + (size_t)n * 256);
  float* a_ts = a_st + nf;
  float* st   = a_ts + nf;
  unsigned short* wfrag = (unsigned short*)(st + 3072);
  unsigned short* wfA  = wfrag;
  unsigned short* wfW2 = wfrag + 2 * 16384;
  unsigned short* wfU1 = wfrag + 3 * 16384;
  unsigned short* wfU2 = wfrag + 6 * 16384;
  unsigned short* wfWe = wfrag + 7 * 16384;        // 2048 shorts (fp16)
  int* sS = (int*)(wfWe + 2048);
  int* sD = sS + E;
  unsigned short* EAh = (unsigned short*)(sD + E);
  int* counts = (int*)(EAh + (size_t)E * 16);
  int* tmp = counts + n;
  int* bsum = tmp + n;

  float invE = 1.0f / (float)E;
  float invN = 1.0f / (float)n;
  int nblk = (n + 63) / 64;
  int nb1 = (n + 1023) / 1024;

  prep_all<<<8, 256, 0, stream>>>(mW1, mW2, uW1, uW2, wfrag);
  hipMemsetAsync(st, 0, 3072 * sizeof(float), stream);
  hipMemsetAsync(a_st, 0, 2 * nf * sizeof(float), stream);
  hipMemsetAsync(counts, 0, (size_t)n * sizeof(int), stream);

  // counting sort by src
  hist_kernel<<<1024, 256, 0, stream>>>(SRC, E, counts);
  scan1<<<nb1, 256, 0, stream>>>(counts, n, tmp, bsum);
  scan2<<<1, 256, 0, stream>>>(bsum, nb1);
  scan3<<<(n + 255) / 256, 256, 0, stream>>>(tmp, bsum, n, counts);
  permute_edges<<<1024, 256, 0, stream>>>(SRC, DST, ea, E, counts, sS, sD, EAh);

  // interleaved fp16 [P|Q] rows
  node_mfma_pq<<<nblk, 256, 0, stream>>>(h, wfA, pqb, n);

  // BN1 stats (sorted edges)
  msg_stats1b<<<2048, 256, 0, stream>>>(pqb, EAh, W1e, sS, sD, E, st);
  bn_finalize<<<1, 128, 0, stream>>>(st + 0,   st + 128, invE, mg1, mbe1, st + 1536, st + 1664);
  bn_finalize<<<1, 128, 0, stream>>>(st + 256, st + 384, invE, mg1, mbe1, st + 1792, st + 1920);

  // BN2 stats
  msg_mfma10<false><<<1536, 256, 0, stream>>>(
      pqb, EAh, wfWe, wfW2, sS, sD, E, st + 1536, nullptr, st + 512, nullptr, nullptr);
  bn_finalize<<<1, 128, 0, stream>>>(st + 512, st + 640, invE, mg2, mbe2, st + 2048, st + 2176);
  bn_finalize<<<1, 128, 0, stream>>>(st + 768, st + 896, invE, mg2, mbe2, st + 2304, st + 2432);

  // recompute + BN2+ReLU + merged scatter
  msg_mfma10<true><<<1536, 256, 0, stream>>>(
      pqb, EAh, wfWe, wfW2, sS, sD, E, st + 1536, st + 2048, nullptr, a_st, a_ts);

  // u1 = h@uW1a + 0.5*a_st@uW1b + 0.5*a_ts@uW1c -> pqb region (fp32)
  float* u1 = (float*)pqb;
  node_mfma<false><<<nblk, 256, 0, stream>>>(h, a_st, a_ts, wfU1,
                                             u1, n, 1, st + 1024, st + 1152, 3);
  bn_finalize<<<1, 128, 0, stream>>>(st + 1024, st + 1152, invN, ug1, ube1, st + 2560, st + 2688);

  // u1p (bf16) -> a_st region ; u2 -> a_ts region
  unsigned short* u1p = (unsigned short*)a_st;
  float* u2 = a_ts;
  prescale_relu<<<2048, 256, 0, stream>>>(u1, st + 2560, (unsigned*)u1p, n);
  node_mfma<true><<<nblk, 256, 0, stream>>>(u1p, nullptr, nullptr, wfU2,
                                            u2, n, 1, st + 1280, st + 1408, 1);
  bn_finalize<<<1, 128, 0, stream>>>(st + 1280, st + 1408, invN, ug2, ube2, st + 2816, st + 2944);

  bn_relu_out<<<2048, 256, 0, stream>>>(u2, st + 2816, (float*)d_out, (long)n * 128);
}

// Round 19
// 2426.283 us; speedup vs baseline: 1.0200x; 1.0037x over previous
//
#include <hip/hip_runtime.h>

#define EPS_BN 1e-5f

typedef __bf16 bf16x8 __attribute__((ext_vector_type(8)));
typedef _Float16 h4 __attribute__((ext_vector_type(4)));
typedef _Float16 h8 __attribute__((ext_vector_type(8)));
typedef float f32x4 __attribute__((ext_vector_type(4)));
typedef unsigned short us8 __attribute__((ext_vector_type(8)));
typedef unsigned short us4 __attribute__((ext_vector_type(4)));
typedef unsigned int u32x4 __attribute__((ext_vector_type(4)));

__device__ __forceinline__ unsigned short f2bf(float x) {
  unsigned u = __builtin_bit_cast(unsigned, x);
  unsigned r = (u + 0x7fffu + ((u >> 16) & 1u)) >> 16;
  return (unsigned short)r;
}
__device__ __forceinline__ unsigned pack2bf(float a, float b) {
  return (unsigned)f2bf(a) | ((unsigned)f2bf(b) << 16);
}
__device__ __forceinline__ unsigned short f2h(float x) {
  return __builtin_bit_cast(unsigned short, (_Float16)x);
}
__device__ __forceinline__ unsigned pack2h(float a, float b) {
  return (unsigned)f2h(a) | ((unsigned)f2h(b) << 16);
}
__device__ __forceinline__ float ubf(unsigned short u) {
  return __builtin_bit_cast(float, (unsigned)u << 16);
}
__device__ __forceinline__ h4 relu4(h4 x) {
  h4 z = {(_Float16)0.f, (_Float16)0.f, (_Float16)0.f, (_Float16)0.f};
  return __builtin_elementwise_max(x, z);
}

// fragment-order index for a [128k x 128n] weight
__device__ __forceinline__ int fragidx(int k, int c) {
  int nf = c >> 4, lr = c & 15, ks = k >> 5, lq = (k >> 3) & 3, j = k & 7;
  return ((((nf << 2) + ks) << 6) | (lq << 4) | lr) * 8 + j;
}

// ---------------------------------------------------------------------------
// One-time weight conversion: [0]=W1a [1]=W1b [2]=W2(fp16) [3..5]=U1(0.5 on 1,2)
// [6]=U2  [7]=We (16x128 fp16 row-major, 2048 shorts)
// ---------------------------------------------------------------------------
__global__ __launch_bounds__(256) void prep_all(
    const float* __restrict__ mW1, const float* __restrict__ mW2,
    const float* __restrict__ uW1, const float* __restrict__ uW2,
    unsigned short* __restrict__ wfrag) {
  int b = blockIdx.x;
  if (b == 7) {
    const float* s7 = mW1 + 256 * 128;
    unsigned short* oc = wfrag + 7L * 16384;
    for (int i = threadIdx.x; i < 2048; i += 256) oc[i] = f2h(s7[i]);
    return;
  }
  const float* src;
  float sc = 1.f;
  switch (b) {
    case 0: src = mW1; break;
    case 1: src = mW1 + 16384; break;
    case 2: src = mW2; break;
    case 3: src = uW1; break;
    case 4: src = uW1 + 16384; sc = 0.5f; break;
    case 5: src = uW1 + 32768; sc = 0.5f; break;
    default: src = uW2; break;
  }
  unsigned short* oc = wfrag + (long)b * 16384;
  bool fp16 = (b == 2);
  for (int i = threadIdx.x; i < 16384; i += 256) {
    float v = src[i] * sc;
    oc[fragidx(i >> 7, i & 127)] = fp16 ? f2h(v) : f2bf(v);
  }
}

// ---------------------------------------------------------------------------
// Counting sort by src: hist -> 2-level exclusive scan -> permute.
// ---------------------------------------------------------------------------
__global__ __launch_bounds__(256) void hist_kernel(
    const int* __restrict__ SRC, long E, int* __restrict__ counts) {
  long i = (long)blockIdx.x * 256 + threadIdx.x;
  long str = (long)gridDim.x * 256;
  for (; i < E; i += str) atomicAdd(&counts[SRC[i]], 1);
}

__global__ __launch_bounds__(256) void scan1(
    const int* __restrict__ counts, int n, int* __restrict__ tmp,
    int* __restrict__ bsum) {
  __shared__ int sd[256];
  int b = blockIdx.x, tid = threadIdx.x;
  int base = b * 1024 + tid * 4;
  int c[4], t = 0;
  #pragma unroll
  for (int j = 0; j < 4; ++j) {
    int idx = base + j;
    c[j] = (idx < n) ? counts[idx] : 0;
    t += c[j];
  }
  sd[tid] = t;
  __syncthreads();
  for (int off = 1; off < 256; off <<= 1) {
    int v = (tid >= off) ? sd[tid - off] : 0;
    __syncthreads();
    sd[tid] += v;
    __syncthreads();
  }
  int run = sd[tid] - t;
  #pragma unroll
  for (int j = 0; j < 4; ++j) {
    int idx = base + j;
    if (idx < n) tmp[idx] = run;
    run += c[j];
  }
  if (tid == 255) bsum[b] = sd[255];
}

__global__ __launch_bounds__(256) void scan2(int* __restrict__ bsum, int nb) {
  __shared__ int sd[256];
  int tid = threadIdx.x;
  int v = (tid < nb) ? bsum[tid] : 0;
  sd[tid] = v;
  __syncthreads();
  for (int off = 1; off < 256; off <<= 1) {
    int x = (tid >= off) ? sd[tid - off] : 0;
    __syncthreads();
    sd[tid] += x;
    __syncthreads();
  }
  if (tid < nb) bsum[tid] = sd[tid] - v;
}

__global__ __launch_bounds__(256) void scan3(
    const int* __restrict__ tmp, const int* __restrict__ bsum, int n,
    int* __restrict__ cursor) {
  int i = blockIdx.x * 256 + threadIdx.x;
  if (i < n) cursor[i] = tmp[i] + bsum[i >> 10];
}

__global__ __launch_bounds__(256) void permute_edges(
    const int* __restrict__ SRC, const int* __restrict__ DST,
    const float* __restrict__ EA, long E, int* __restrict__ cursor,
    int* __restrict__ sS, int* __restrict__ sD,
    unsigned short* __restrict__ EAh) {
  long i = (long)blockIdx.x * 256 + threadIdx.x;
  long str = (long)gridDim.x * 256;
  for (; i < E; i += str) {
    int s = SRC[i];
    int pos = atomicAdd(&cursor[s], 1);
    sS[pos] = s;
    sD[pos] = DST[i];
    const float4* ep = (const float4*)(EA + i * 16);
    float4 a = ep[0], b = ep[1], c = ep[2], d = ep[3];
    u32x4 lo, hi;
    lo[0] = pack2h(a.x, a.y); lo[1] = pack2h(a.z, a.w);
    lo[2] = pack2h(b.x, b.y); lo[3] = pack2h(b.z, b.w);
    hi[0] = pack2h(c.x, c.y); hi[1] = pack2h(c.z, c.w);
    hi[2] = pack2h(d.x, d.y); hi[3] = pack2h(d.z, d.w);
    *(u32x4*)(EAh + (long)pos * 16) = lo;
    *(u32x4*)(EAh + (long)pos * 16 + 8) = hi;
  }
}

// ---------------------------------------------------------------------------
// Merged node GEMM: emits interleaved fp16 [P|Q] rows (256 shorts/node).
// ---------------------------------------------------------------------------
__global__ __launch_bounds__(256) void node_mfma_pq(
    const float* __restrict__ h, const unsigned short* __restrict__ WfA,
    unsigned short* __restrict__ pqb, int n) {
  __shared__ unsigned short WT[16384];
  int tid = threadIdx.x;
  int lid = tid & 63, w = tid >> 6, lr = lid & 15, lq = lid >> 4;
  long rbase = (long)blockIdx.x * 64 + 16 * w;
  long r = rbase + lr;
  bool rv = (r < n);
  long rl = rv ? r : 0;
  const us8* WF8 = (const us8*)WT;

  bf16x8 af[4];
  const float* Ar = h + rl * 128;
  #pragma unroll
  for (int ks = 0; ks < 4; ++ks) {
    int e0 = 32 * ks + 8 * lq;
    float4 x = *(const float4*)(Ar + e0);
    float4 y = *(const float4*)(Ar + e0 + 4);
    u32x4 t;
    t[0] = pack2bf(x.x, x.y); t[1] = pack2bf(x.z, x.w);
    t[2] = pack2bf(y.x, y.y); t[3] = pack2bf(y.z, y.w);
    if (!rv) { t[0] = 0; t[1] = 0; t[2] = 0; t[3] = 0; }
    af[ks] = __builtin_bit_cast(bf16x8, t);
  }

  f32x4 accP[8], accQ[8];
  #pragma unroll
  for (int nf = 0; nf < 8; ++nf) {
    accP[nf] = f32x4{0.f, 0.f, 0.f, 0.f};
    accQ[nf] = f32x4{0.f, 0.f, 0.f, 0.f};
  }

  for (int i = tid; i < 2048; i += 256) ((us8*)WT)[i] = ((const us8*)WfA)[i];
  __syncthreads();
  #pragma unroll
  for (int nf = 0; nf < 8; ++nf) {
    #pragma unroll
    for (int ks = 0; ks < 4; ++ks) {
      bf16x8 bf = __builtin_bit_cast(bf16x8, WF8[(nf * 4 + ks) * 64 + lid]);
      accP[nf] = __builtin_amdgcn_mfma_f32_16x16x32_bf16(af[ks], bf, accP[nf], 0, 0, 0);
    }
  }
  __syncthreads();
  for (int i = tid; i < 2048; i += 256) ((us8*)WT)[i] = ((const us8*)(WfA + 16384))[i];
  __syncthreads();
  #pragma unroll
  for (int nf = 0; nf < 8; ++nf) {
    #pragma unroll
    for (int ks = 0; ks < 4; ++ks) {
      bf16x8 bf = __builtin_bit_cast(bf16x8, WF8[(nf * 4 + ks) * 64 + lid]);
      accQ[nf] = __builtin_amdgcn_mfma_f32_16x16x32_bf16(af[ks], bf, accQ[nf], 0, 0, 0);
    }
  }

  #pragma unroll
  for (int nf = 0; nf < 8; ++nf) {
    #pragma unroll
    for (int i = 0; i < 4; ++i) {
      long nd = rbase + 4 * lq + i;
      if (nd < n) {
        int ch = 16 * nf + lr;
        pqb[nd * 256 + ch] = f2h(accP[nf][i]);
        pqb[nd * 256 + 128 + ch] = f2h(accQ[nf][i]);
      }
    }
  }
}

// ---------------------------------------------------------------------------
// General node MFMA GEMM (nk chunks, frag-order bf16 weights) with stats.
// ---------------------------------------------------------------------------
template <bool ABF16>
__global__ __launch_bounds__(256) void node_mfma(
    const void* A0, const void* A1, const void* A2,
    const unsigned short* __restrict__ Wf,
    float* __restrict__ C, int n, int dostats,
    float* __restrict__ sum_out, float* __restrict__ ssq_out, int nk) {
  __shared__ unsigned short WT[16384];
  int tid = threadIdx.x;
  int lid = tid & 63, w = tid >> 6, lr = lid & 15, lq = lid >> 4;
  long rbase = (long)blockIdx.x * 64 + 16 * w;

  const void* As[3] = {A0, A1, A2};
  f32x4 acc[8];
  #pragma unroll
  for (int nf = 0; nf < 8; ++nf) acc[nf] = f32x4{0.f, 0.f, 0.f, 0.f};

  long r = rbase + lr;
  bool rv = (r < n);
  long rl = rv ? r : 0;
  const us8* WF8 = (const us8*)WT;

  for (int c = 0; c < nk; ++c) {
    if (c) __syncthreads();
    const us8* src = (const us8*)(Wf + (long)c * 16384);
    for (int i = tid; i < 2048; i += 256) ((us8*)WT)[i] = src[i];
    __syncthreads();

    bf16x8 af[4];
    if (ABF16) {
      const us8* Ar = (const us8*)((const unsigned short*)As[c] + rl * 128);
      #pragma unroll
      for (int ks = 0; ks < 4; ++ks) {
        us8 v = Ar[ks * 4 + lq];
        if (!rv) v = us8{0, 0, 0, 0, 0, 0, 0, 0};
        af[ks] = __builtin_bit_cast(bf16x8, v);
      }
    } else {
      const float* Ar = (const float*)As[c] + rl * 128;
      #pragma unroll
      for (int ks = 0; ks < 4; ++ks) {
        int e0 = 32 * ks + 8 * lq;
        float4 x = *(const float4*)(Ar + e0);
        float4 y = *(const float4*)(Ar + e0 + 4);
        u32x4 t;
        t[0] = pack2bf(x.x, x.y); t[1] = pack2bf(x.z, x.w);
        t[2] = pack2bf(y.x, y.y); t[3] = pack2bf(y.z, y.w);
        if (!rv) { t[0] = 0; t[1] = 0; t[2] = 0; t[3] = 0; }
        af[ks] = __builtin_bit_cast(bf16x8, t);
      }
    }
    #pragma unroll
    for (int nf = 0; nf < 8; ++nf) {
      #pragma unroll
      for (int ks = 0; ks < 4; ++ks) {
        bf16x8 bf = __builtin_bit_cast(bf16x8, WF8[(nf * 4 + ks) * 64 + lid]);
        acc[nf] = __builtin_amdgcn_mfma_f32_16x16x32_bf16(af[ks], bf, acc[nf], 0, 0, 0);
      }
    }
  }

  float lsum[8], lssq[8];
  #pragma unroll
  for (int nf = 0; nf < 8; ++nf) { lsum[nf] = 0.f; lssq[nf] = 0.f; }
  #pragma unroll
  for (int nf = 0; nf < 8; ++nf) {
    #pragma unroll
    for (int i = 0; i < 4; ++i) {
      long nd = rbase + 4 * lq + i;
      if (nd < n) {
        float v = acc[nf][i];
        C[nd * 128 + 16 * nf + lr] = v;
        lsum[nf] += v; lssq[nf] += v * v;
      }
    }
  }
  if (dostats) {
    #pragma unroll
    for (int nf = 0; nf < 8; ++nf) {
      float v0 = lsum[nf]; v0 += __shfl_xor(v0, 16); v0 += __shfl_xor(v0, 32);
      float v1 = lssq[nf]; v1 += __shfl_xor(v1, 16); v1 += __shfl_xor(v1, 32);
      if (lq == 0) {
        atomicAdd(&sum_out[16 * nf + lr], v0);
        atomicAdd(&ssq_out[16 * nf + lr], v1);
      }
    }
  }
}

// ---------------------------------------------------------------------------
// BN1 stats over sorted edges, fp16 PQ rows + fp16 ea.
// ---------------------------------------------------------------------------
__global__ __launch_bounds__(256) void msg_stats1b(
    const unsigned short* __restrict__ PQ,
    const unsigned short* __restrict__ EAh, const float* __restrict__ W1e,
    const int* __restrict__ SRC, const int* __restrict__ DST, long E,
    float* __restrict__ stats) {
  __shared__ float Wel[16][128];
  __shared__ float red[32][16];
  int tid = threadIdx.x;
  for (int i = tid; i < 16 * 128; i += 256) ((float*)Wel)[i] = W1e[i];
  for (int i = tid; i < 512; i += 256) ((float*)red)[i] = 0.f;
  __syncthreads();
  int c4 = tid & 31, grp = tid >> 5;
  float4 s_st = {0,0,0,0}, q_st = {0,0,0,0}, s_ts = {0,0,0,0}, q_ts = {0,0,0,0};
  long stride = (long)gridDim.x * 8;
  for (long e = (long)blockIdx.x * 8 + grp; e < E; e += stride) {
    int s = SRC[e], t = DST[e];
    const unsigned short* Rs = PQ + (long)s * 256;
    const unsigned short* Rt = PQ + (long)t * 256;
    h4 Ps = __builtin_bit_cast(h4, *(const us4*)(Rs + 4 * c4));
    h4 Qs = __builtin_bit_cast(h4, *(const us4*)(Rs + 128 + 4 * c4));
    h4 Pt = __builtin_bit_cast(h4, *(const us4*)(Rt + 4 * c4));
    h4 Qt = __builtin_bit_cast(h4, *(const us4*)(Rt + 128 + 4 * c4));
    h8 elo = __builtin_bit_cast(h8, *(const us8*)(EAh + e * 16));
    h8 ehi = __builtin_bit_cast(h8, *(const us8*)(EAh + e * 16 + 8));
    float rx = 0.f, ry = 0.f, rz = 0.f, rw = 0.f;
    #pragma unroll
    for (int k = 0; k < 16; ++k) {
      float f = (k < 8) ? (float)elo[k & 7] : (float)ehi[k & 7];
      const float4 w4 = *(const float4*)&Wel[k][c4 * 4];
      rx = fmaf(f, w4.x, rx); ry = fmaf(f, w4.y, ry);
      rz = fmaf(f, w4.z, rz); rw = fmaf(f, w4.w, rw);
    }
    float zx = (float)Ps[0] + (float)Qt[0] + rx, zy = (float)Ps[1] + (float)Qt[1] + ry;
    float zz = (float)Ps[2] + (float)Qt[2] + rz, zw = (float)Ps[3] + (float)Qt[3] + rw;
    s_st.x += zx; s_st.y += zy; s_st.z += zz; s_st.w += zw;
    q_st.x += zx * zx; q_st.y += zy * zy; q_st.z += zz * zz; q_st.w += zw * zw;
    float ux = (float)Pt[0] + (float)Qs[0] + rx, uy = (float)Pt[1] + (float)Qs[1] + ry;
    float uz = (float)Pt[2] + (float)Qs[2] + rz, uw = (float)Pt[3] + (float)Qs[3] + rw;
    s_ts.x += ux; s_ts.y += uy; s_ts.z += uz; s_ts.w += uw;
    q_ts.x += ux * ux; q_ts.y += uy * uy; q_ts.z += uz * uz; q_ts.w += uw * uw;
  }
  atomicAdd(&red[c4][0], s_st.x);  atomicAdd(&red[c4][1], s_st.y);
  atomicAdd(&red[c4][2], s_st.z);  atomicAdd(&red[c4][3], s_st.w);
  atomicAdd(&red[c4][4], q_st.x);  atomicAdd(&red[c4][5], q_st.y);
  atomicAdd(&red[c4][6], q_st.z);  atomicAdd(&red[c4][7], q_st.w);
  atomicAdd(&red[c4][8], s_ts.x);  atomicAdd(&red[c4][9], s_ts.y);
  atomicAdd(&red[c4][10], s_ts.z); atomicAdd(&red[c4][11], s_ts.w);
  atomicAdd(&red[c4][12], q_ts.x); atomicAdd(&red[c4][13], q_ts.y);
  atomicAdd(&red[c4][14], q_ts.z); atomicAdd(&red[c4][15], q_ts.w);
  __syncthreads();
  #pragma unroll
  for (int rep = 0; rep < 2; ++rep) {
    int j = rep * 256 + tid;
    int cc = j >> 4, k = j & 15, group = k >> 2, comp = k & 3;
    atomicAdd(&stats[group * 128 + cc * 4 + comp], red[cc][k]);
  }
}

// ---------------------------------------------------------------------------
// Edge MFMA pass v11 (STATS + fp16 y-store): fp16 packed phase A, f16 MFMA,
// dbuf (one barrier/tile, B-then-A), setprio. Phase B stores y rows to ybuf.
// ---------------------------------------------------------------------------
__global__ __launch_bounds__(256) void msg_mfma11(
    const unsigned short* __restrict__ PQ,
    const unsigned short* __restrict__ EAh,
    const unsigned short* __restrict__ Weh,
    const unsigned short* __restrict__ W2f,
    const int* __restrict__ SRC, const int* __restrict__ DST, long E,
    const float* __restrict__ sc1, float* __restrict__ stats2,
    unsigned short* __restrict__ ybuf) {
  __shared__ unsigned short W2F[16384];
  __shared__ unsigned short Atile[2][2][32][136];

  int tid = threadIdx.x;
  int c4 = tid & 31;
  int slot = tid >> 5;
  int lid = tid & 63, w = tid >> 6, lr = lid & 15, lq = lid >> 4;
  int dir = w >> 1;
  int half = (w & 1) * 16;

  for (int i = tid; i < 2048; i += 256) ((us8*)W2F)[i] = ((const us8*)W2f)[i];
  const us8* W2F8 = (const us8*)W2F;

  h4 wreg[16];
  #pragma unroll
  for (int k = 0; k < 16; ++k)
    wreg[k] = __builtin_bit_cast(h4, *(const us4*)(Weh + k * 128 + c4 * 4));

  int ch0 = c4 * 4;
  h4 scst4 = {(_Float16)sc1[ch0], (_Float16)sc1[ch0 + 1],
              (_Float16)sc1[ch0 + 2], (_Float16)sc1[ch0 + 3]};
  h4 shst4 = {(_Float16)sc1[128 + ch0], (_Float16)sc1[128 + ch0 + 1],
              (_Float16)sc1[128 + ch0 + 2], (_Float16)sc1[128 + ch0 + 3]};
  h4 scts4 = {(_Float16)sc1[256 + ch0], (_Float16)sc1[256 + ch0 + 1],
              (_Float16)sc1[256 + ch0 + 2], (_Float16)sc1[256 + ch0 + 3]};
  h4 shts4 = {(_Float16)sc1[384 + ch0], (_Float16)sc1[384 + ch0 + 1],
              (_Float16)sc1[384 + ch0 + 2], (_Float16)sc1[384 + ch0 + 3]};

  float ssum[8], sssq[8];
  #pragma unroll
  for (int nf = 0; nf < 8; ++nf) { ssum[nf] = 0.f; sssq[nf] = 0.f; }

  long tb0 = (long)blockIdx.x * 32;
  long tstep = (long)gridDim.x * 32;

  auto phaseA = [&](long tb, int p) {
    int nE = (int)(E - tb < 32 ? E - tb : 32);
    #pragma unroll
    for (int rep = 0; rep < 4; ++rep) {
      int er = rep * 8 + slot;
      if (er < nE) {
        long e = tb + er;
        int s = SRC[e], t = DST[e];
        const us4* Rs = (const us4*)(PQ + (long)s * 256);
        const us4* Rt = (const us4*)(PQ + (long)t * 256);
        h4 Ps = __builtin_bit_cast(h4, Rs[c4]);
        h4 Qs = __builtin_bit_cast(h4, Rs[32 + c4]);
        h4 Pt = __builtin_bit_cast(h4, Rt[c4]);
        h4 Qt = __builtin_bit_cast(h4, Rt[32 + c4]);
        h8 elo = __builtin_bit_cast(h8, *(const us8*)(EAh + e * 16));
        h8 ehi = __builtin_bit_cast(h8, *(const us8*)(EAh + e * 16 + 8));
        h4 r = {(_Float16)0.f, (_Float16)0.f, (_Float16)0.f, (_Float16)0.f};
        #pragma unroll
        for (int k = 0; k < 16; ++k) {
          _Float16 f = (k < 8) ? elo[k & 7] : ehi[k & 7];
          h4 fv = {f, f, f, f};
          r += fv * wreg[k];
        }
        h4 zst = relu4((Ps + Qt + r) * scst4 + shst4);
        h4 zts = relu4((Pt + Qs + r) * scts4 + shts4);
        *(unsigned long long*)&Atile[p][0][er][ch0] =
            __builtin_bit_cast(unsigned long long, zst);
        *(unsigned long long*)&Atile[p][1][er][ch0] =
            __builtin_bit_cast(unsigned long long, zts);
      } else {
        *(unsigned long long*)&Atile[p][0][er][ch0] = 0ull;
        *(unsigned long long*)&Atile[p][1][er][ch0] = 0ull;
      }
    }
  };

  if (tb0 < E) phaseA(tb0, 0);
  __syncthreads();

  int p = 0;
  for (long tb = tb0; tb < E; tb += tstep) {
    int nE = (int)(E - tb < 32 ? E - tb : 32);
    long tnext = tb + tstep;

    int arow = half + lr;
    const char* ap = (const char*)&Atile[p][dir][arow][0];
    int acolb = lq * 16;
    h8 af[4];
    #pragma unroll
    for (int ks = 0; ks < 4; ++ks) {
      af[ks] = *(const h8*)(ap + ks * 64 + acolb);
    }
    f32x4 acc[8];
    __builtin_amdgcn_s_setprio(1);
    #pragma unroll
    for (int nf = 0; nf < 8; ++nf) {
      acc[nf] = f32x4{0.f, 0.f, 0.f, 0.f};
      #pragma unroll
      for (int ks = 0; ks < 4; ++ks) {
        h8 bf = __builtin_bit_cast(h8, W2F8[(nf * 4 + ks) * 64 + lid]);
        acc[nf] = __builtin_amdgcn_mfma_f32_16x16x32_f16(af[ks], bf, acc[nf], 0, 0, 0);
      }
    }
    __builtin_amdgcn_s_setprio(0);

    if (tnext < E) phaseA(tnext, p ^ 1);

    // stats + y store
    #pragma unroll
    for (int nf = 0; nf < 8; ++nf) {
      int ch = 16 * nf + lr;
      #pragma unroll
      for (int i = 0; i < 4; ++i) {
        float v = acc[nf][i];
        ssum[nf] += v; sssq[nf] += v * v;
        int row = half + 4 * lq + i;
        if (row < nE) ybuf[(tb + row) * 256 + dir * 128 + ch] = f2h(v);
      }
    }
    __syncthreads();
    p ^= 1;
  }

  #pragma unroll
  for (int nf = 0; nf < 8; ++nf) {
    float v0 = ssum[nf]; v0 += __shfl_xor(v0, 16); v0 += __shfl_xor(v0, 32);
    float v1 = sssq[nf]; v1 += __shfl_xor(v1, 16); v1 += __shfl_xor(v1, 32);
    if (lq == 0) {
      int ch = 16 * nf + lr;
      atomicAdd(&stats2[dir * 256 + ch], v0);
      atomicAdd(&stats2[dir * 256 + 128 + ch], v1);
    }
  }
}

// ---------------------------------------------------------------------------
// Streaming scatter: sequential y reads (sorted by src), affine+ReLU,
// per-channel run-merged atomics. Thread = (dir, channel).
// ---------------------------------------------------------------------------
__global__ __launch_bounds__(256) void scatter_stream(
    const unsigned short* __restrict__ Y, const int* __restrict__ sS, long E,
    const float* __restrict__ sc2,
    float* __restrict__ a_st, float* __restrict__ a_ts) {
  __shared__ unsigned short Yl[8][256];
  __shared__ int Sl[8];
  int tid = threadIdx.x;
  int dir = tid >> 7, ch = tid & 127;
  float s2 = sc2[dir * 256 + ch];
  float h2 = sc2[dir * 256 + 128 + ch];
  float* accOut = dir ? a_ts : a_st;
  long eper = (E + gridDim.x - 1) / gridDim.x;
  long e0 = (long)blockIdx.x * eper;
  long e1 = e0 + eper; if (e1 > E) e1 = E;
  int run_src = -1;
  float run_acc = 0.f;
  for (long cb = e0; cb < e1; cb += 8) {
    int cnt = (int)((e1 - cb < 8) ? (e1 - cb) : 8);
    int le = tid >> 5, lo = (tid & 31) * 8;
    if (le < cnt)
      *(us8*)&Yl[le][lo] = *(const us8*)(Y + (cb + le) * 256 + lo);
    if (tid < cnt) Sl[tid] = sS[cb + tid];
    __syncthreads();
    for (int i = 0; i < cnt; ++i) {
      float y = (float)__builtin_bit_cast(_Float16, Yl[i][dir * 128 + ch]);
      float v = fmaxf(fmaf(y, s2, h2), 0.f);
      int s = Sl[i];
      if (s == run_src) {
        run_acc += v;
      } else {
        if (run_src >= 0 && run_acc != 0.f)
          atomicAdd(&accOut[(long)run_src * 128 + ch], run_acc);
        run_src = s; run_acc = v;
      }
    }
    __syncthreads();
  }
  if (run_src >= 0 && run_acc != 0.f)
    atomicAdd(&accOut[(long)run_src * 128 + ch], run_acc);
}

// ---------------------------------------------------------------------------
// FALLBACK edge MFMA pass v10 (R18): stats / recompute+scatter.
// ---------------------------------------------------------------------------
template <bool SCATTER>
__global__ __launch_bounds__(256) void msg_mfma10(
    const unsigned short* __restrict__ PQ,
    const unsigned short* __restrict__ EAh,
    const unsigned short* __restrict__ Weh,
    const unsigned short* __restrict__ W2f,
    const int* __restrict__ SRC, const int* __restrict__ DST, long E,
    const float* __restrict__ sc1, const float* __restrict__ sc2,
    float* __restrict__ stats2,
    float* __restrict__ a_st, float* __restrict__ a_ts) {
  __shared__ unsigned short W2F[16384];
  __shared__ unsigned short Atile[2][2][32][136];
  __shared__ int sArr[2][32];

  int tid = threadIdx.x;
  int c4 = tid & 31;
  int slot = tid >> 5;
  int lid = tid & 63, w = tid >> 6, lr = lid & 15, lq = lid >> 4;
  int dir = w >> 1;
  int half = (w & 1) * 16;

  for (int i = tid; i < 2048; i += 256) ((us8*)W2F)[i] = ((const us8*)W2f)[i];
  const us8* W2F8 = (const us8*)W2F;

  h4 wreg[16];
  #pragma unroll
  for (int k = 0; k < 16; ++k)
    wreg[k] = __builtin_bit_cast(h4, *(const us4*)(Weh + k * 128 + c4 * 4));

  int ch0 = c4 * 4;
  h4 scst4 = {(_Float16)sc1[ch0], (_Float16)sc1[ch0 + 1],
              (_Float16)sc1[ch0 + 2], (_Float16)sc1[ch0 + 3]};
  h4 shst4 = {(_Float16)sc1[128 + ch0], (_Float16)sc1[128 + ch0 + 1],
              (_Float16)sc1[128 + ch0 + 2], (_Float16)sc1[128 + ch0 + 3]};
  h4 scts4 = {(_Float16)sc1[256 + ch0], (_Float16)sc1[256 + ch0 + 1],
              (_Float16)sc1[256 + ch0 + 2], (_Float16)sc1[256 + ch0 + 3]};
  h4 shts4 = {(_Float16)sc1[384 + ch0], (_Float16)sc1[384 + ch0 + 1],
              (_Float16)sc1[384 + ch0 + 2], (_Float16)sc1[384 + ch0 + 3]};

  float s2[8], h2p[8];
  float ssum[8], sssq[8];
  if constexpr (SCATTER) {
    const float* scd = sc2 + dir * 256;
    #pragma unroll
    for (int nf = 0; nf < 8; ++nf) {
      int ch = 16 * nf + lr;
      s2[nf] = scd[ch]; h2p[nf] = scd[128 + ch];
    }
  } else {
    #pragma unroll
    for (int nf = 0; nf < 8; ++nf) { ssum[nf] = 0.f; sssq[nf] = 0.f; }
  }
  float* accOut = dir ? a_ts : a_st;

  long tb0 = (long)blockIdx.x * 32;
  long tstep = (long)gridDim.x * 32;

  auto phaseA = [&](long tb, int p) {
    int nE = (int)(E - tb < 32 ? E - tb : 32);
    #pragma unroll
    for (int rep = 0; rep < 4; ++rep) {
      int er = rep * 8 + slot;
      if (er < nE) {
        long e = tb + er;
        int s = SRC[e], t = DST[e];
        if (SCATTER && c4 == 0) sArr[p][er] = s;
        const us4* Rs = (const us4*)(PQ + (long)s * 256);
        const us4* Rt = (const us4*)(PQ + (long)t * 256);
        h4 Ps = __builtin_bit_cast(h4, Rs[c4]);
        h4 Qs = __builtin_bit_cast(h4, Rs[32 + c4]);
        h4 Pt = __builtin_bit_cast(h4, Rt[c4]);
        h4 Qt = __builtin_bit_cast(h4, Rt[32 + c4]);
        h8 elo = __builtin_bit_cast(h8, *(const us8*)(EAh + e * 16));
        h8 ehi = __builtin_bit_cast(h8, *(const us8*)(EAh + e * 16 + 8));
        h4 r = {(_Float16)0.f, (_Float16)0.f, (_Float16)0.f, (_Float16)0.f};
        #pragma unroll
        for (int k = 0; k < 16; ++k) {
          _Float16 f = (k < 8) ? elo[k & 7] : ehi[k & 7];
          h4 fv = {f, f, f, f};
          r += fv * wreg[k];
        }
        h4 zst = relu4((Ps + Qt + r) * scst4 + shst4);
        h4 zts = relu4((Pt + Qs + r) * scts4 + shts4);
        *(unsigned long long*)&Atile[p][0][er][ch0] =
            __builtin_bit_cast(unsigned long long, zst);
        *(unsigned long long*)&Atile[p][1][er][ch0] =
            __builtin_bit_cast(unsigned long long, zts);
      } else {
        *(unsigned long long*)&Atile[p][0][er][ch0] = 0ull;
        *(unsigned long long*)&Atile[p][1][er][ch0] = 0ull;
      }
    }
  };

  if (tb0 < E) phaseA(tb0, 0);
  __syncthreads();

  int p = 0;
  for (long tb = tb0; tb < E; tb += tstep) {
    int nE = (int)(E - tb < 32 ? E - tb : 32);
    long tnext = tb + tstep;

    int arow = half + lr;
    const char* ap = (const char*)&Atile[p][dir][arow][0];
    int acolb = lq * 16;
    h8 af[4];
    #pragma unroll
    for (int ks = 0; ks < 4; ++ks) {
      af[ks] = *(const h8*)(ap + ks * 64 + acolb);
    }
    int srow[4];
    bool uniform = false;
    int usrc = -1;
    if constexpr (SCATTER) {
      #pragma unroll
      for (int i = 0; i < 4; ++i) {
        int row = half + 4 * lq + i;
        srow[i] = (row < nE) ? sArr[p][row] : -1;
      }
      if (half + 15 < nE) {
        usrc = sArr[p][half];
        uniform = (usrc == sArr[p][half + 15]);
      }
    }
    f32x4 acc[8];
    __builtin_amdgcn_s_setprio(1);
    #pragma unroll
    for (int nf = 0; nf < 8; ++nf) {
      acc[nf] = f32x4{0.f, 0.f, 0.f, 0.f};
      #pragma unroll
      for (int ks = 0; ks < 4; ++ks) {
        h8 bf = __builtin_bit_cast(h8, W2F8[(nf * 4 + ks) * 64 + lid]);
        acc[nf] = __builtin_amdgcn_mfma_f32_16x16x32_f16(af[ks], bf, acc[nf], 0, 0, 0);
      }
    }
    __builtin_amdgcn_s_setprio(0);

    if (tnext < E) phaseA(tnext, p ^ 1);

    #pragma unroll
    for (int nf = 0; nf < 8; ++nf) {
      if constexpr (SCATTER) {
        int ch = 16 * nf + lr;
        if (uniform) {
          float m = 0.f;
          #pragma unroll
          for (int i = 0; i < 4; ++i)
            m += fmaxf(fmaf(acc[nf][i], s2[nf], h2p[nf]), 0.f);
          m += __shfl_xor(m, 16);
          m += __shfl_xor(m, 32);
          if (lq == 0 && m != 0.f)
            atomicAdd(&accOut[(long)usrc * 128 + ch], m);
        } else {
          int cur = srow[0];
          float m = fmaxf(fmaf(acc[nf][0], s2[nf], h2p[nf]), 0.f);
          #pragma unroll
          for (int i = 1; i < 4; ++i) {
            float v = fmaxf(fmaf(acc[nf][i], s2[nf], h2p[nf]), 0.f);
            if (srow[i] == cur) {
              m += v;
            } else {
              if (cur >= 0 && m != 0.f) atomicAdd(&accOut[(long)cur * 128 + ch], m);
              cur = srow[i]; m = v;
            }
          }
          if (cur >= 0 && m != 0.f) atomicAdd(&accOut[(long)cur * 128 + ch], m);
        }
      } else {
        #pragma unroll
        for (int i = 0; i < 4; ++i) {
          ssum[nf] += acc[nf][i]; sssq[nf] += acc[nf][i] * acc[nf][i];
        }
      }
    }
    __syncthreads();
    p ^= 1;
  }

  if constexpr (!SCATTER) {
    #pragma unroll
    for (int nf = 0; nf < 8; ++nf) {
      float v0 = ssum[nf]; v0 += __shfl_xor(v0, 16); v0 += __shfl_xor(v0, 32);
      float v1 = sssq[nf]; v1 += __shfl_xor(v1, 16); v1 += __shfl_xor(v1, 32);
      if (lq == 0) {
        int ch = 16 * nf + lr;
        atomicAdd(&stats2[dir * 256 + ch], v0);
        atomicAdd(&stats2[dir * 256 + 128 + ch], v1);
      }
    }
  }
}

__global__ void bn_finalize(const float* __restrict__ sum, const float* __restrict__ ssq,
                            float invN, const float* __restrict__ g,
                            const float* __restrict__ be,
                            float* __restrict__ sc, float* __restrict__ sh) {
  int j = threadIdx.x;
  float m = sum[j] * invN;
  float v = ssq[j] * invN - m * m;
  float s = g[j] * rsqrtf(v + EPS_BN);
  sc[j] = s;
  sh[j] = be[j] - m * s;
}

__global__ __launch_bounds__(256) void prescale_relu(
    const float* __restrict__ X, const float* __restrict__ scsh,
    unsigned* __restrict__ out, long nrows) {
  long gid = (long)blockIdx.x * 256 + threadIdx.x;
  int c2 = (int)(gid & 63);
  float s0 = scsh[2 * c2], s1 = scsh[2 * c2 + 1];
  float h0 = scsh[128 + 2 * c2], h1 = scsh[128 + 2 * c2 + 1];
  const float2* X2 = (const float2*)X;
  long rstride = ((long)gridDim.x * 256) >> 6;
  for (long row = gid >> 6; row < nrows; row += rstride) {
    float2 x = X2[row * 64 + c2];
    out[row * 64 + c2] = pack2bf(fmaxf(fmaf(x.x, s0, h0), 0.f),
                                 fmaxf(fmaf(x.y, s1, h1), 0.f));
  }
}

__global__ __launch_bounds__(256) void bn_relu_out(
    const float* __restrict__ U2, const float* __restrict__ scsh,
    float* __restrict__ out, long total) {
  long i = (long)blockIdx.x * blockDim.x + threadIdx.x;
  long stride = (long)gridDim.x * blockDim.x;
  for (; i < total; i += stride) {
    int j = (int)(i & 127);
    out[i] = fmaxf(fmaf(U2[i], scsh[j], scsh[128 + j]), 0.f);
  }
}

extern "C" void kernel_launch(void* const* d_in, const int* in_sizes, int n_in,
                              void* d_out, int out_size, void* d_ws, size_t ws_size,
                              hipStream_t stream) {
  const float* h    = (const float*)d_in[0];
  const int*   ei   = (const int*)d_in[1];
  const float* ea   = (const float*)d_in[2];
  const float* mW1  = (const float*)d_in[3];
  const float* mg1  = (const float*)d_in[5];
  const float* mbe1 = (const float*)d_in[6];
  const float* mW2  = (const float*)d_in[7];
  const float* mg2  = (const float*)d_in[9];
  const float* mbe2 = (const float*)d_in[10];
  const float* uW1  = (const float*)d_in[11];
  const float* ug1  = (const float*)d_in[13];
  const float* ube1 = (const float*)d_in[14];
  const float* uW2  = (const float*)d_in[15];
  const float* ug2  = (const float*)d_in[17];
  const float* ube2 = (const float*)d_in[18];

  int n = in_sizes[0] / 128;
  long E = (long)(in_sizes[1] / 2);
  const int* SRC = ei;
  const int* DST = ei + E;
  const float* W1e = mW1 + 256 * 128;

  size_t nf = (size_t)n * 128;
  unsigned short* pqb = (unsigned short*)d_ws;
  float* a_st = (float*)(pqb + (size_t)n * 256);
  float* a_ts = a_st + nf;
  float* st   = a_ts + nf;
  unsigned short* wfrag = (unsigned short*)(st + 3072);
  unsigned short* wfA  = wfrag;
  unsigned short* wfW2 = wfrag + 2 * 16384;
  unsigned short* wfU1 = wfrag + 3 * 16384;
  unsigned short* wfU2 = wfrag + 6 * 16384;
  unsigned short* wfWe = wfrag + 7 * 16384;        // 2048 shorts (fp16)
  int* sS = (int*)(wfWe + 2048);
  int* sD = sS + E;
  unsigned short* EAh = (unsigned short*)(sD + E);
  int* counts = (int*)(EAh + (size_t)E * 16);
  int* tmp = counts + n;
  int* bsum = tmp + n;
  unsigned short* ybuf = (unsigned short*)(bsum + 256);
  size_t needY = (size_t)((char*)(ybuf + (size_t)E * 256) - (char*)d_ws);
  bool matY = (ws_size >= needY);

  float invE = 1.0f / (float)E;
  float invN = 1.0f / (float)n;
  int nblk = (n + 63) / 64;
  int nb1 = (n + 1023) / 1024;

  prep_all<<<8, 256, 0, stream>>>(mW1, mW2, uW1, uW2, wfrag);
  hipMemsetAsync(st, 0, 3072 * sizeof(float), stream);
  hipMemsetAsync(a_st, 0, 2 * nf * sizeof(float), stream);
  hipMemsetAsync(counts, 0, (size_t)n * sizeof(int), stream);

  // counting sort by src
  hist_kernel<<<1024, 256, 0, stream>>>(SRC, E, counts);
  scan1<<<nb1, 256, 0, stream>>>(counts, n, tmp, bsum);
  scan2<<<1, 256, 0, stream>>>(bsum, nb1);
  scan3<<<(n + 255) / 256, 256, 0, stream>>>(tmp, bsum, n, counts);
  permute_edges<<<1024, 256, 0, stream>>>(SRC, DST, ea, E, counts, sS, sD, EAh);

  // interleaved fp16 [P|Q] rows
  node_mfma_pq<<<nblk, 256, 0, stream>>>(h, wfA, pqb, n);

  // BN1 stats (sorted edges)
  msg_stats1b<<<2048, 256, 0, stream>>>(pqb, EAh, W1e, sS, sD, E, st);
  bn_finalize<<<1, 128, 0, stream>>>(st + 0,   st + 128, invE, mg1, mbe1, st + 1536, st + 1664);
  bn_finalize<<<1, 128, 0, stream>>>(st + 256, st + 384, invE, mg1, mbe1, st + 1792, st + 1920);

  if (matY) {
    // single MFMA pass: BN2 stats + fp16 y materialization
    msg_mfma11<<<1536, 256, 0, stream>>>(
        pqb, EAh, wfWe, wfW2, sS, sD, E, st + 1536, st + 512, ybuf);
    bn_finalize<<<1, 128, 0, stream>>>(st + 512, st + 640, invE, mg2, mbe2, st + 2048, st + 2176);
    bn_finalize<<<1, 128, 0, stream>>>(st + 768, st + 896, invE, mg2, mbe2, st + 2304, st + 2432);
    // streaming scatter from materialized y
    scatter_stream<<<2048, 256, 0, stream>>>(ybuf, sS, E, st + 2048, a_st, a_ts);
  } else {
    // fallback: R18 two-pass recompute
    msg_mfma10<false><<<1536, 256, 0, stream>>>(
        pqb, EAh, wfWe, wfW2, sS, sD, E, st + 1536, nullptr, st + 512, nullptr, nullptr);
    bn_finalize<<<1, 128, 0, stream>>>(st + 512, st + 640, invE, mg2, mbe2, st + 2048, st + 2176);
    bn_finalize<<<1, 128, 0, stream>>>(st + 768, st + 896, invE, mg2, mbe2, st + 2304, st + 2432);
    msg_mfma10<true><<<1536, 256, 0, stream>>>(
        pqb, EAh, wfWe, wfW2, sS, sD, E, st + 1536, st + 2048, nullptr, a_st, a_ts);
  }

  // u1 = h@uW1a + 0.5*a_st@uW1b + 0.5*a_ts@uW1c -> pqb region (fp32)
  float* u1 = (float*)pqb;
  node_mfma<false><<<nblk, 256, 0, stream>>>(h, a_st, a_ts, wfU1,
                                             u1, n, 1, st + 1024, st + 1152, 3);
  bn_finalize<<<1, 128, 0, stream>>>(st + 1024, st + 1152, invN, ug1, ube1, st + 2560, st + 2688);

  // u1p (bf16) -> a_st region ; u2 -> a_ts region
  unsigned short* u1p = (unsigned short*)a_st;
  float* u2 = a_ts;
  prescale_relu<<<2048, 256, 0, stream>>>(u1, st + 2560, (unsigned*)u1p, n);
  node_mfma<true><<<nblk, 256, 0, stream>>>(u1p, nullptr, nullptr, wfU2,
                                            u2, n, 1, st + 1280, st + 1408, 1);
  bn_finalize<<<1, 128, 0, stream>>>(st + 1280, st + 1408, invN, ug2, ube2, st + 2816, st + 2944);

  bn_relu_out<<<2048, 256, 0, stream>>>(u2, st + 2816, (float*)d_out, (long)n * 128);
}